// Round 6
// baseline (1605.135 us; speedup 1.0000x reference)
//
#include <hip/hip_runtime.h>
#include <math.h>

#define BATCH 4096
#define L0 117
#define L1 234
#define L2 468
#define L3 937
#define L4 1875
#define L5 3750
#define JC 512
#define NTAB (L1 + L2 + L3 + L4 + L5)          // 7264 upsample-table entries
#define NBT  (L0 + L1 + L2 + L3 + L4)          // 3631 band-table entries
#define NSTATS (16 + 5 * 64 * 16)              // stats0 + 5 stages x 64 buckets x 16

static __device__ __forceinline__ float lrelu(float v) { return v >= 0.f ? v : 0.2f * v; }

// ---------------------------------------------------------------- setup ----
// ti0/tw upsample tables + zero all stats. Rebuilt every launch (ws poisoned).
__global__ void k_setup(double* __restrict__ stats, int* __restrict__ ti0,
                        float4* __restrict__ tw)
{
    int s = blockIdx.x;
    if (s == 0)
        for (int i = threadIdx.x; i < NSTATS; i += blockDim.x) stats[i] = 0.0;
    const int Lin[5]  = {L0, L1, L2, L3, L4};
    const int Lout[5] = {L1, L2, L3, L4, L5};
    const int Uoff[5] = {0, L1, L1 + L2, L1 + L2 + L3, L1 + L2 + L3 + L4};
    int li = Lin[s], lo = Lout[s], off = Uoff[s];
    float scale = (float)((double)li / (double)lo);
    const float A = -0.75f;
    for (int j = threadIdx.x; j < lo; j += blockDim.x) {
        float src = ((float)j + 0.5f) * scale - 0.5f;
        float fi = floorf(src);
        float t = src - fi;
        float u;
        float4 w;
        u = t + 1.f; w.x = ((A * u - 5.f * A) * u + 8.f * A) * u - 4.f * A;
        u = t;       w.y = ((A + 2.f) * u - (A + 3.f)) * u * u + 1.f;
        u = 1.f - t; w.z = ((A + 2.f) * u - (A + 3.f)) * u * u + 1.f;
        u = 2.f - t; w.w = ((A * u - 5.f * A) * u + 8.f * A) * u - 4.f * A;
        ti0[off + j] = (int)fi;
        tw[off + j] = w;
    }
}

// Band tables: colsum[q] = sum of weights mapping v[q] -> any z[j];
// band[q][d] = sum over ordered tap pairs (q, q+d) of w_k*w_l.
// Gives  sum_j z[j]   = sum_q colsum[q] v[q]
//        sum_j z[j]^2 = sum_q sum_d band[q][d] v[q] v[q+d]     (exact).
__global__ __launch_bounds__(256) void k_setup2(float* __restrict__ colsum,
                                                float4* __restrict__ band)
{
    __shared__ float cs[1880];
    __shared__ float bd[1880][4];
    int s = blockIdx.x;
    const int Lin[5]  = {L0, L1, L2, L3, L4};
    const int Lout[5] = {L1, L2, L3, L4, L5};
    const int Toff[5] = {0, L0, L0 + L1, L0 + L1 + L2, L0 + L1 + L2 + L3};
    int li = Lin[s], lo = Lout[s], off = Toff[s];
    for (int i = threadIdx.x; i < li; i += 256) {
        cs[i] = 0.f; bd[i][0] = 0.f; bd[i][1] = 0.f; bd[i][2] = 0.f; bd[i][3] = 0.f;
    }
    __syncthreads();
    float scale = (float)((double)li / (double)lo);
    const float A = -0.75f;
    for (int j = threadIdx.x; j < lo; j += 256) {
        float src = ((float)j + 0.5f) * scale - 0.5f;
        float fi = floorf(src);
        float t = src - fi;
        int i0 = (int)fi;
        float u, w[4];
        u = t + 1.f; w[0] = ((A * u - 5.f * A) * u + 8.f * A) * u - 4.f * A;
        u = t;       w[1] = ((A + 2.f) * u - (A + 3.f)) * u * u + 1.f;
        u = 1.f - t; w[2] = ((A + 2.f) * u - (A + 3.f)) * u * u + 1.f;
        u = 2.f - t; w[3] = ((A * u - 5.f * A) * u + 8.f * A) * u - 4.f * A;
        int q[4];
#pragma unroll
        for (int k = 0; k < 4; k++) q[k] = min(max(i0 - 1 + k, 0), li - 1);
#pragma unroll
        for (int k = 0; k < 4; k++) atomicAdd(&cs[q[k]], w[k]);
#pragma unroll
        for (int k = 0; k < 4; k++)
#pragma unroll
            for (int l = 0; l < 4; l++) {
                int qa = q[k], qb = q[l];
                int qm = min(qa, qb), d = abs(qa - qb);
                atomicAdd(&bd[qm][d], w[k] * w[l]);
            }
    }
    __syncthreads();
    for (int i = threadIdx.x; i < li; i += 256) {
        colsum[off + i] = cs[i];
        band[off + i] = make_float4(bd[i][0], bd[i][1], bd[i][2], bd[i][3]);
    }
}

// ------------------------------------------------- input GEMM + bn0 stats ----
__global__ __launch_bounds__(256) void k0a(const float* __restrict__ x,
                                           const float* __restrict__ Wi,
                                           const float* __restrict__ bi,
                                           float* __restrict__ oi,
                                           double* __restrict__ stats)
{
    __shared__ float As[32][68];
    __shared__ float Bs[32][132];
    __shared__ float red[512];
    int m0 = blockIdx.y * 64;
    int n0 = blockIdx.x * 128;
    int tid = threadIdx.x;
    int tm = tid >> 4, tn = tid & 15;
    float acc[4][8];
#pragma unroll
    for (int r = 0; r < 4; r++)
#pragma unroll
        for (int c = 0; c < 8; c++) acc[r][c] = 0.f;

    for (int k0 = 0; k0 < 160; k0 += 32) {
        for (int e = tid; e < 64 * 32; e += 256) {
            int m = e >> 5, k = e & 31;
            As[k][m] = x[(size_t)(m0 + m) * 160 + k0 + k];
        }
        for (int e = tid; e < 128 * 32; e += 256) {
            int n = e >> 5, k = e & 31;
            int row = n0 + n;
            Bs[k][n] = (row < 936) ? Wi[(size_t)row * 160 + k0 + k] : 0.f;
        }
        __syncthreads();
#pragma unroll
        for (int k = 0; k < 32; k++) {
            float4 av = *(const float4*)&As[k][tm * 4];
            float4 bv0 = *(const float4*)&Bs[k][tn * 8];
            float4 bv1 = *(const float4*)&Bs[k][tn * 8 + 4];
            float a[4] = {av.x, av.y, av.z, av.w};
            float b[8] = {bv0.x, bv0.y, bv0.z, bv0.w, bv1.x, bv1.y, bv1.z, bv1.w};
#pragma unroll
            for (int r = 0; r < 4; r++)
#pragma unroll
                for (int c = 0; c < 8; c++) acc[r][c] = fmaf(a[r], b[c], acc[r][c]);
        }
        __syncthreads();
    }
    float lsum = 0.f, lsq = 0.f;
#pragma unroll
    for (int r = 0; r < 4; r++) {
        int row = m0 + tm * 4 + r;
        int col = n0 + tn * 8;
        float vals[8];
#pragma unroll
        for (int c = 0; c < 8; c++) {
            float v = (col + c < 936) ? acc[r][c] + bi[col + c] : 0.f;
            vals[c] = v;
            lsum += v;
            lsq += v * v;
        }
        if (col + 7 < 936) {
            *(float4*)&oi[(size_t)row * 936 + col] = make_float4(vals[0], vals[1], vals[2], vals[3]);
            *(float4*)&oi[(size_t)row * 936 + col + 4] = make_float4(vals[4], vals[5], vals[6], vals[7]);
        } else {
            for (int c = 0; c < 8; c++)
                if (col + c < 936) oi[(size_t)row * 936 + col + c] = vals[c];
        }
    }
    red[tid] = lsum;
    red[256 + tid] = lsq;
    __syncthreads();
    for (int st = 128; st > 0; st >>= 1) {
        if (tid < st) { red[tid] += red[tid + st]; red[256 + tid] += red[256 + tid + st]; }
        __syncthreads();
    }
    if (tid == 0) {
        atomicAdd(&stats[0], (double)red[0]);
        atomicAdd(&stats[1], (double)red[256]);
    }
}

// ------------- bn0 apply + class branch -> v1 = W1·h0, + z1 band stats ----
__global__ __launch_bounds__(128) void k0b(const float* __restrict__ oi,
                                           const float* __restrict__ emb,
                                           const int* __restrict__ y,
                                           const float* __restrict__ Wc,
                                           const float* __restrict__ bc,
                                           const float* __restrict__ g0,
                                           const float* __restrict__ b0,
                                           const float* __restrict__ w1,
                                           const double* __restrict__ st0,
                                           double* __restrict__ z1out,
                                           const float* __restrict__ colsum1,
                                           const float4* __restrict__ band1,
                                           float* __restrict__ v1)
{
    __shared__ float embs[50], W1s[72];
    __shared__ float sa_s, sc_s;
    __shared__ float vs[117][9];
    __shared__ float red[2][16];
    int b = blockIdx.x, tid = threadIdx.x;
    if (tid < 50) embs[tid] = emb[y[b] * 50 + tid];
    else if (tid < 122) W1s[tid - 50] = w1[tid - 50];
    else if (tid == 122) {
        double N = (double)BATCH * 936.0;
        double m = st0[0] / N;
        double var = st0[1] / N - m * m;
        double a = (double)g0[0] / sqrt(var + 1e-5);
        sa_s = (float)a;
        sc_s = (float)((double)b0[0] - m * a);
    }
    __syncthreads();
    float ls[8], lq[8];
#pragma unroll
    for (int o = 0; o < 8; o++) { ls[o] = 0.f; lq[o] = 0.f; }
    if (tid < 117) {
        float oc = bc[tid];
        for (int k = 0; k < 50; k++) oc = fmaf(embs[k], Wc[tid * 50 + k], oc);
        float h[9];
#pragma unroll
        for (int c = 0; c < 8; c++)
            h[c] = lrelu(fmaf(oi[(size_t)b * 936 + c * 117 + tid], sa_s, sc_s));
        h[8] = oc;
        float vn[8];
#pragma unroll
        for (int o = 0; o < 8; o++) {
            float a2 = 0.f;
#pragma unroll
            for (int c = 0; c < 9; c++) a2 = fmaf(W1s[o * 9 + c], h[c], a2);
            vn[o] = a2;
        }
        float* dp = v1 + ((size_t)b * 117 + tid) * 8;
        *(float4*)dp = make_float4(vn[0], vn[1], vn[2], vn[3]);
        *(float4*)(dp + 4) = make_float4(vn[4], vn[5], vn[6], vn[7]);
#pragma unroll
        for (int o = 0; o < 8; o++) vs[tid][o] = vn[o];
    }
    __syncthreads();
    if (tid < 117) {
        float csv = colsum1[tid];
        float4 bdv = band1[tid];
#pragma unroll
        for (int o = 0; o < 8; o++) {
            float v0 = vs[tid][o];
            ls[o] = fmaf(csv, v0, ls[o]);
            float t = bdv.x * v0;
            if (tid + 1 < 117) t = fmaf(bdv.y, vs[tid + 1][o], t);
            if (tid + 2 < 117) t = fmaf(bdv.z, vs[tid + 2][o], t);
            if (tid + 3 < 117) t = fmaf(bdv.w, vs[tid + 3][o], t);
            lq[o] = fmaf(v0, t, lq[o]);
        }
    }
#pragma unroll
    for (int o = 0; o < 8; o++)
        for (int off = 32; off > 0; off >>= 1) {
            ls[o] += __shfl_down(ls[o], off, 64);
            lq[o] += __shfl_down(lq[o], off, 64);
        }
    int wave = tid >> 6, lane = tid & 63;
    if (lane == 0)
#pragma unroll
        for (int o = 0; o < 8; o++) { red[wave][o] = ls[o]; red[wave][8 + o] = lq[o]; }
    __syncthreads();
    if (tid < 16)
        atomicAdd(&z1out[(b & 63) * 16 + tid], (double)(red[0][tid] + red[1][tid]));
}

// --------------------------------------------------- unified stage kernel ----
// Stage s: reads v_s, applies bn_s (stats from zin buckets) + lrelu, computes
// v_{s+1} = W_{s+1}·h_s, writes it (if vout) and accumulates z_{s+1} band stats.
__global__ __launch_bounds__(256, 4) void k_stage(
    const float* __restrict__ vin, float* __restrict__ vout,
    const float* __restrict__ W, const float* __restrict__ g,
    const float* __restrict__ bb,
    const double* __restrict__ zin, double* __restrict__ zout,
    const float* __restrict__ colsum, const float4* __restrict__ band,
    const int* __restrict__ ti0, const float4* __restrict__ tw,
    int Lin, int Lout, int nchunk)
{
    __shared__ float Ws[64], aa[8], cc[8];
    __shared__ float vs[JC + 3][9];
    __shared__ float red[4][16];
    int tid = threadIdx.x;
    if (tid < 64) Ws[tid] = W[tid];
    if (tid < 8) {
        double s = 0.0, q = 0.0;
        for (int k = 0; k < 64; k++) { s += zin[k * 16 + tid]; q += zin[k * 16 + 8 + tid]; }
        double N = (double)BATCH * (double)Lout;
        double m = s / N;
        double var = q / N - m * m;
        double a = (double)g[tid] / sqrt(var + 1e-5);
        aa[tid] = (float)a;
        cc[tid] = (float)((double)bb[tid] - m * a);
    }
    __syncthreads();
    int b = blockIdx.x / nchunk, ch = blockIdx.x - b * nchunk;
    int j0 = ch * JC, j1 = min(j0 + JC, Lout), je = min(j1 + 3, Lout);
    const float* vb = vin + (size_t)b * Lin * 8;
    // phase A: compute v_{s+1} for [j0, je), write [j0, j1) to global, all to LDS
    for (int jj = tid; jj < je - j0; jj += 256) {
        int j = j0 + jj;
        int i0 = ti0[j];
        float4 w = tw[j];
        float wk[4] = {w.x, w.y, w.z, w.w};
        float z[8] = {0.f, 0.f, 0.f, 0.f, 0.f, 0.f, 0.f, 0.f};
#pragma unroll
        for (int k = 0; k < 4; k++) {
            int q = min(max(i0 - 1 + k, 0), Lin - 1);
            float4 p0 = *(const float4*)(vb + q * 8);
            float4 p1 = *(const float4*)(vb + q * 8 + 4);
            z[0] = fmaf(wk[k], p0.x, z[0]); z[1] = fmaf(wk[k], p0.y, z[1]);
            z[2] = fmaf(wk[k], p0.z, z[2]); z[3] = fmaf(wk[k], p0.w, z[3]);
            z[4] = fmaf(wk[k], p1.x, z[4]); z[5] = fmaf(wk[k], p1.y, z[5]);
            z[6] = fmaf(wk[k], p1.z, z[6]); z[7] = fmaf(wk[k], p1.w, z[7]);
        }
        float h[8];
#pragma unroll
        for (int c = 0; c < 8; c++) h[c] = lrelu(fmaf(z[c], aa[c], cc[c]));
        float vn[8];
#pragma unroll
        for (int o = 0; o < 8; o++) {
            float a2 = 0.f;
#pragma unroll
            for (int c = 0; c < 8; c++) a2 = fmaf(Ws[o * 8 + c], h[c], a2);
            vn[o] = a2;
        }
        if (vout != nullptr && jj < j1 - j0) {
            float* dp = vout + ((size_t)b * Lout + j) * 8;
            *(float4*)dp = make_float4(vn[0], vn[1], vn[2], vn[3]);
            *(float4*)(dp + 4) = make_float4(vn[4], vn[5], vn[6], vn[7]);
        }
#pragma unroll
        for (int o = 0; o < 8; o++) vs[jj][o] = vn[o];
    }
    __syncthreads();
    // phase B: banded stats for z_{s+1} over positions [j0, j1)
    float ls[8], lq[8];
#pragma unroll
    for (int o = 0; o < 8; o++) { ls[o] = 0.f; lq[o] = 0.f; }
    int nst = j1 - j0, ne = je - j0;
    for (int jj = tid; jj < nst; jj += 256) {
        int p = j0 + jj;
        float csv = colsum[p];
        float4 bdv = band[p];
#pragma unroll
        for (int o = 0; o < 8; o++) {
            float v0 = vs[jj][o];
            ls[o] = fmaf(csv, v0, ls[o]);
            float t = bdv.x * v0;
            if (jj + 1 < ne) t = fmaf(bdv.y, vs[jj + 1][o], t);
            if (jj + 2 < ne) t = fmaf(bdv.z, vs[jj + 2][o], t);
            if (jj + 3 < ne) t = fmaf(bdv.w, vs[jj + 3][o], t);
            lq[o] = fmaf(v0, t, lq[o]);
        }
    }
#pragma unroll
    for (int o = 0; o < 8; o++)
        for (int off = 32; off > 0; off >>= 1) {
            ls[o] += __shfl_down(ls[o], off, 64);
            lq[o] += __shfl_down(lq[o], off, 64);
        }
    int wave = tid >> 6, lane = tid & 63;
    if (lane == 0)
#pragma unroll
        for (int o = 0; o < 8; o++) { red[wave][o] = ls[o]; red[wave][8 + o] = lq[o]; }
    __syncthreads();
    if (tid < 16) {
        float v = red[0][tid] + red[1][tid] + red[2][tid] + red[3][tid];
        atomicAdd(&zout[(blockIdx.x & 63) * 16 + tid], (double)v);
    }
}

// ----------------- final fused kernel: v4 -> h4 -> v5 (LDS) -> h5 -> out ----
__global__ __launch_bounds__(256, 4) void k_final(
    const float* __restrict__ v4, float* __restrict__ out,
    const float* __restrict__ W5, const float* __restrict__ w6,
    const float* __restrict__ g4, const float* __restrict__ b4,
    const float* __restrict__ g5, const float* __restrict__ b5,
    const double* __restrict__ z4st, const double* __restrict__ z5st,
    const int* __restrict__ ti04, const float4* __restrict__ tw4,
    const int* __restrict__ ti05, const float4* __restrict__ tw5)
{
    __shared__ float W5s[64], w6s[8], a4[8], c4[8], a5[8], c5[8];
    __shared__ float v5s[272][9];
    int tid = threadIdx.x;
    if (tid < 64) W5s[tid] = W5[tid];
    if (tid < 8) {
        w6s[tid] = w6[tid];
        double s = 0.0, q = 0.0;
        for (int k = 0; k < 64; k++) { s += z4st[k * 16 + tid]; q += z4st[k * 16 + 8 + tid]; }
        double N4 = (double)BATCH * (double)L4;
        double m = s / N4;
        double var = q / N4 - m * m;
        double a = (double)g4[tid] / sqrt(var + 1e-5);
        a4[tid] = (float)a;
        c4[tid] = (float)((double)b4[tid] - m * a);
        s = 0.0; q = 0.0;
        for (int k = 0; k < 64; k++) { s += z5st[k * 16 + tid]; q += z5st[k * 16 + 8 + tid]; }
        double N5 = (double)BATCH * (double)L5;
        m = s / N5;
        var = q / N5 - m * m;
        a = (double)g5[tid] / sqrt(var + 1e-5);
        a5[tid] = (float)a;
        c5[tid] = (float)((double)b5[tid] - m * a);
    }
    __syncthreads();
    int b = blockIdx.x >> 3, ch = blockIdx.x & 7;
    int j0 = ch * JC, j1 = min(j0 + JC, L5);
    int plo = max(0, ti05[j0] - 1);
    int phi = min(L4 - 1, ti05[j1 - 1] + 2);
    int NP = phi - plo + 1;
    const float* vb = v4 + (size_t)b * L3 * 8;
    // phase A: v5 for needed p-range into LDS
    for (int pp = tid; pp < NP; pp += 256) {
        int p = plo + pp;
        int i0 = ti04[p];
        float4 w = tw4[p];
        float wk[4] = {w.x, w.y, w.z, w.w};
        float z[8] = {0.f, 0.f, 0.f, 0.f, 0.f, 0.f, 0.f, 0.f};
#pragma unroll
        for (int k = 0; k < 4; k++) {
            int q = min(max(i0 - 1 + k, 0), L3 - 1);
            float4 p0 = *(const float4*)(vb + q * 8);
            float4 p1 = *(const float4*)(vb + q * 8 + 4);
            z[0] = fmaf(wk[k], p0.x, z[0]); z[1] = fmaf(wk[k], p0.y, z[1]);
            z[2] = fmaf(wk[k], p0.z, z[2]); z[3] = fmaf(wk[k], p0.w, z[3]);
            z[4] = fmaf(wk[k], p1.x, z[4]); z[5] = fmaf(wk[k], p1.y, z[5]);
            z[6] = fmaf(wk[k], p1.z, z[6]); z[7] = fmaf(wk[k], p1.w, z[7]);
        }
        float h[8];
#pragma unroll
        for (int c = 0; c < 8; c++) h[c] = lrelu(fmaf(z[c], a4[c], c4[c]));
#pragma unroll
        for (int o = 0; o < 8; o++) {
            float a2 = 0.f;
#pragma unroll
            for (int c = 0; c < 8; c++) a2 = fmaf(W5s[o * 8 + c], h[c], a2);
            v5s[pp][o] = a2;
        }
    }
    __syncthreads();
    // phase B: upsample v5 -> bn5 -> lrelu -> dot w6 -> out
    for (int jj = tid; jj < j1 - j0; jj += 256) {
        int j = j0 + jj;
        int i0 = ti05[j];
        float4 w = tw5[j];
        float wk[4] = {w.x, w.y, w.z, w.w};
        float z[8] = {0.f, 0.f, 0.f, 0.f, 0.f, 0.f, 0.f, 0.f};
#pragma unroll
        for (int k = 0; k < 4; k++) {
            int pp = min(max(i0 - 1 + k, 0), L4 - 1) - plo;
            const float* vp = v5s[pp];
#pragma unroll
            for (int o = 0; o < 8; o++) z[o] = fmaf(wk[k], vp[o], z[o]);
        }
        float r = 0.f;
#pragma unroll
        for (int o = 0; o < 8; o++)
            r = fmaf(w6s[o], lrelu(fmaf(z[o], a5[o], c5[o])), r);
        out[(size_t)b * L5 + j] = r;
    }
}

// ---------------------------------------------------------------- launch ----
extern "C" void kernel_launch(void* const* d_in, const int* in_sizes, int n_in,
                              void* d_out, int out_size, void* d_ws, size_t ws_size,
                              hipStream_t stream)
{
    const float* x   = (const float*)d_in[0];
    const int*   y   = (const int*)d_in[1];
    const float* emb = (const float*)d_in[2];
    const float* Wc  = (const float*)d_in[3];
    const float* bc  = (const float*)d_in[4];
    const float* Wi  = (const float*)d_in[5];
    const float* bi  = (const float*)d_in[6];
    const float* g0  = (const float*)d_in[7];
    const float* b0  = (const float*)d_in[8];
    const float* w1  = (const float*)d_in[9];
    const float* w2  = (const float*)d_in[10];
    const float* w3  = (const float*)d_in[11];
    const float* w4  = (const float*)d_in[12];
    const float* w5  = (const float*)d_in[13];
    const float* w6  = (const float*)d_in[14];
    const float* g1  = (const float*)d_in[15];
    const float* b1  = (const float*)d_in[16];
    const float* g2  = (const float*)d_in[17];
    const float* b2  = (const float*)d_in[18];
    const float* g3  = (const float*)d_in[19];
    const float* b3  = (const float*)d_in[20];
    const float* g4  = (const float*)d_in[21];
    const float* b4  = (const float*)d_in[22];
    const float* g5  = (const float*)d_in[23];
    const float* b5  = (const float*)d_in[24];
    float* out = (float*)d_out;

    char* ws = (char*)d_ws;
    size_t off = 0;
    auto alloc = [&](size_t bytes) {
        size_t r = off;
        off += (bytes + 255) & ~(size_t)255;
        return r;
    };
    double* stats  = (double*)(ws + alloc(NSTATS * sizeof(double)));
    int*    ti0    = (int*)(ws + alloc((size_t)NTAB * sizeof(int)));
    float4* tw     = (float4*)(ws + alloc((size_t)NTAB * sizeof(float4)));
    float*  colsum = (float*)(ws + alloc((size_t)NBT * sizeof(float)));
    float4* band   = (float4*)(ws + alloc((size_t)NBT * sizeof(float4)));
    float*  oi     = (float*)(ws + alloc((size_t)BATCH * 936 * 4));
    float*  bufA   = (float*)(ws + alloc((size_t)BATCH * L2 * 8 * 4));   // v1 / v3
    float*  bufB   = (float*)(ws + alloc((size_t)BATCH * L3 * 8 * 4));   // v2 / v4

    double* st0  = stats;
    double* zst1 = stats + 16;
    double* zst2 = stats + 16 + 1024;
    double* zst3 = stats + 16 + 2048;
    double* zst4 = stats + 16 + 3072;
    double* zst5 = stats + 16 + 4096;

    // upsample-table offsets (length Lout per stage)
    const int u1 = 0, u2 = L1, u3 = L1 + L2, u4 = L1 + L2 + L3, u5 = L1 + L2 + L3 + L4;
    // band-table offsets (length Lin per stage)
    const int t1 = 0, t2 = L0, t3 = L0 + L1, t4 = L0 + L1 + L2, t5 = L0 + L1 + L2 + L3;

    float* v1 = bufA;
    float* v2 = bufB;
    float* v3 = bufA;
    float* v4 = bufB;

    k_setup<<<5, 256, 0, stream>>>(stats, ti0, tw);
    k_setup2<<<5, 256, 0, stream>>>(colsum, band);
    k0a<<<dim3(8, 64), 256, 0, stream>>>(x, Wi, bi, oi, st0);
    k0b<<<BATCH, 128, 0, stream>>>(oi, emb, y, Wc, bc, g0, b0, w1, st0, zst1,
                                   colsum + t1, band + t1, v1);
    // s1: v1 -> v2  (bn1, W2, z2 stats)
    k_stage<<<BATCH, 256, 0, stream>>>(v1, v2, w2, g1, b1, zst1, zst2,
                                       colsum + t2, band + t2, ti0 + u1, tw + u1, L0, L1, 1);
    // s2: v2 -> v3  (bn2, W3, z3 stats)
    k_stage<<<BATCH, 256, 0, stream>>>(v2, v3, w3, g2, b2, zst2, zst3,
                                       colsum + t3, band + t3, ti0 + u2, tw + u2, L1, L2, 1);
    // s3: v3 -> v4  (bn3, W4, z4 stats)
    k_stage<<<BATCH * 2, 256, 0, stream>>>(v3, v4, w4, g3, b3, zst3, zst4,
                                           colsum + t4, band + t4, ti0 + u3, tw + u3, L2, L3, 2);
    // s4: v4 -> (transient v5), z5 stats only
    k_stage<<<BATCH * 4, 256, 0, stream>>>(v4, nullptr, w5, g4, b4, zst4, zst5,
                                           colsum + t5, band + t5, ti0 + u4, tw + u4, L3, L4, 4);
    // s5: v4 -> h4 -> v5 -> h5 -> out
    k_final<<<BATCH * 8, 256, 0, stream>>>(v4, out, w5, w6, g4, b4, g5, b5, zst4, zst5,
                                           ti0 + u4, tw + u4, ti0 + u5, tw + u5);
}

// Round 8
// 1225.183 us; speedup vs baseline: 1.3101x; 1.3101x over previous
//
#include <hip/hip_runtime.h>
#include <math.h>

#define BATCH 4096
#define L0 117
#define L1 234
#define L2 468
#define L3 937
#define L4 1875
#define L5 3750
#define JC 512
#define NTAB (L1 + L2 + L3 + L4 + L5)          // 7264 upsample-table entries
#define NBT  (L0 + L1 + L2 + L3 + L4)          // 3631 band-table entries
#define NSTATS (16 + 5 * 64 * 16)              // stats0 + 5 stages x 64 buckets x 16

static __device__ __forceinline__ float lrelu(float v) { return v >= 0.f ? v : 0.2f * v; }

// ---------------------------------------------------------------- setup ----
__global__ void k_setup(double* __restrict__ stats, int* __restrict__ ti0,
                        float4* __restrict__ tw)
{
    int s = blockIdx.x;
    if (s == 0)
        for (int i = threadIdx.x; i < NSTATS; i += blockDim.x) stats[i] = 0.0;
    const int Lin[5]  = {L0, L1, L2, L3, L4};
    const int Lout[5] = {L1, L2, L3, L4, L5};
    const int Uoff[5] = {0, L1, L1 + L2, L1 + L2 + L3, L1 + L2 + L3 + L4};
    int li = Lin[s], lo = Lout[s], off = Uoff[s];
    float scale = (float)((double)li / (double)lo);
    const float A = -0.75f;
    for (int j = threadIdx.x; j < lo; j += blockDim.x) {
        float src = ((float)j + 0.5f) * scale - 0.5f;
        float fi = floorf(src);
        float t = src - fi;
        float u;
        float4 w;
        u = t + 1.f; w.x = ((A * u - 5.f * A) * u + 8.f * A) * u - 4.f * A;
        u = t;       w.y = ((A + 2.f) * u - (A + 3.f)) * u * u + 1.f;
        u = 1.f - t; w.z = ((A + 2.f) * u - (A + 3.f)) * u * u + 1.f;
        u = 2.f - t; w.w = ((A * u - 5.f * A) * u + 8.f * A) * u - 4.f * A;
        ti0[off + j] = (int)fi;
        tw[off + j] = w;
    }
}

// Band tables (see R2 notes): exact Gram identity for upsample stats.
__global__ __launch_bounds__(256) void k_setup2(float* __restrict__ colsum,
                                                float4* __restrict__ band)
{
    __shared__ float cs[1880];
    __shared__ float bd[1880][4];
    int s = blockIdx.x;
    const int Lin[5]  = {L0, L1, L2, L3, L4};
    const int Lout[5] = {L1, L2, L3, L4, L5};
    const int Toff[5] = {0, L0, L0 + L1, L0 + L1 + L2, L0 + L1 + L2 + L3};
    int li = Lin[s], lo = Lout[s], off = Toff[s];
    for (int i = threadIdx.x; i < li; i += 256) {
        cs[i] = 0.f; bd[i][0] = 0.f; bd[i][1] = 0.f; bd[i][2] = 0.f; bd[i][3] = 0.f;
    }
    __syncthreads();
    float scale = (float)((double)li / (double)lo);
    const float A = -0.75f;
    for (int j = threadIdx.x; j < lo; j += 256) {
        float src = ((float)j + 0.5f) * scale - 0.5f;
        float fi = floorf(src);
        float t = src - fi;
        int i0 = (int)fi;
        float u, w[4];
        u = t + 1.f; w[0] = ((A * u - 5.f * A) * u + 8.f * A) * u - 4.f * A;
        u = t;       w[1] = ((A + 2.f) * u - (A + 3.f)) * u * u + 1.f;
        u = 1.f - t; w[2] = ((A + 2.f) * u - (A + 3.f)) * u * u + 1.f;
        u = 2.f - t; w[3] = ((A * u - 5.f * A) * u + 8.f * A) * u - 4.f * A;
        int q[4];
#pragma unroll
        for (int k = 0; k < 4; k++) q[k] = min(max(i0 - 1 + k, 0), li - 1);
#pragma unroll
        for (int k = 0; k < 4; k++) atomicAdd(&cs[q[k]], w[k]);
#pragma unroll
        for (int k = 0; k < 4; k++)
#pragma unroll
            for (int l = 0; l < 4; l++) {
                int qa = q[k], qb = q[l];
                int qm = min(qa, qb), d = abs(qa - qb);
                atomicAdd(&bd[qm][d], w[k] * w[l]);
            }
    }
    __syncthreads();
    for (int i = threadIdx.x; i < li; i += 256) {
        colsum[off + i] = cs[i];
        band[off + i] = make_float4(bd[i][0], bd[i][1], bd[i][2], bd[i][3]);
    }
}

// ------------------------------------------------- input GEMM + bn0 stats ----
__global__ __launch_bounds__(256) void k0a(const float* __restrict__ x,
                                           const float* __restrict__ Wi,
                                           const float* __restrict__ bi,
                                           float* __restrict__ oi,
                                           double* __restrict__ stats)
{
    __shared__ float As[32][68];
    __shared__ float Bs[32][132];
    __shared__ float red[512];
    int m0 = blockIdx.y * 64;
    int n0 = blockIdx.x * 128;
    int tid = threadIdx.x;
    int tm = tid >> 4, tn = tid & 15;
    float acc[4][8];
#pragma unroll
    for (int r = 0; r < 4; r++)
#pragma unroll
        for (int c = 0; c < 8; c++) acc[r][c] = 0.f;

    for (int k0 = 0; k0 < 160; k0 += 32) {
        for (int e = tid; e < 64 * 32; e += 256) {
            int m = e >> 5, k = e & 31;
            As[k][m] = x[(size_t)(m0 + m) * 160 + k0 + k];
        }
        for (int e = tid; e < 128 * 32; e += 256) {
            int n = e >> 5, k = e & 31;
            int row = n0 + n;
            Bs[k][n] = (row < 936) ? Wi[(size_t)row * 160 + k0 + k] : 0.f;
        }
        __syncthreads();
#pragma unroll
        for (int k = 0; k < 32; k++) {
            float4 av = *(const float4*)&As[k][tm * 4];
            float4 bv0 = *(const float4*)&Bs[k][tn * 8];
            float4 bv1 = *(const float4*)&Bs[k][tn * 8 + 4];
            float a[4] = {av.x, av.y, av.z, av.w};
            float b[8] = {bv0.x, bv0.y, bv0.z, bv0.w, bv1.x, bv1.y, bv1.z, bv1.w};
#pragma unroll
            for (int r = 0; r < 4; r++)
#pragma unroll
                for (int c = 0; c < 8; c++) acc[r][c] = fmaf(a[r], b[c], acc[r][c]);
        }
        __syncthreads();
    }
    float lsum = 0.f, lsq = 0.f;
#pragma unroll
    for (int r = 0; r < 4; r++) {
        int row = m0 + tm * 4 + r;
        int col = n0 + tn * 8;
        float vals[8];
#pragma unroll
        for (int c = 0; c < 8; c++) {
            float v = (col + c < 936) ? acc[r][c] + bi[col + c] : 0.f;
            vals[c] = v;
            lsum += v;
            lsq += v * v;
        }
        if (col + 7 < 936) {
            *(float4*)&oi[(size_t)row * 936 + col] = make_float4(vals[0], vals[1], vals[2], vals[3]);
            *(float4*)&oi[(size_t)row * 936 + col + 4] = make_float4(vals[4], vals[5], vals[6], vals[7]);
        } else {
            for (int c = 0; c < 8; c++)
                if (col + c < 936) oi[(size_t)row * 936 + col + c] = vals[c];
        }
    }
    red[tid] = lsum;
    red[256 + tid] = lsq;
    __syncthreads();
    for (int st = 128; st > 0; st >>= 1) {
        if (tid < st) { red[tid] += red[tid + st]; red[256 + tid] += red[256 + tid + st]; }
        __syncthreads();
    }
    if (tid == 0) {
        atomicAdd(&stats[0], (double)red[0]);
        atomicAdd(&stats[1], (double)red[256]);
    }
}

// ------------- bn0 apply + class branch -> v1 = W1·h0, + z1 band stats ----
__global__ __launch_bounds__(128) void k0b(const float* __restrict__ oi,
                                           const float* __restrict__ emb,
                                           const int* __restrict__ y,
                                           const float* __restrict__ Wc,
                                           const float* __restrict__ bc,
                                           const float* __restrict__ g0,
                                           const float* __restrict__ b0,
                                           const float* __restrict__ w1,
                                           const double* __restrict__ st0,
                                           double* __restrict__ z1out,
                                           const float* __restrict__ colsum1,
                                           const float4* __restrict__ band1,
                                           float* __restrict__ v1)
{
    __shared__ float embs[50], W1s[72];
    __shared__ float sa_s, sc_s;
    __shared__ float vs[117][9];
    __shared__ float red[2][16];
    int b = blockIdx.x, tid = threadIdx.x;
    if (tid < 50) embs[tid] = emb[y[b] * 50 + tid];
    else if (tid < 122) W1s[tid - 50] = w1[tid - 50];
    else if (tid == 122) {
        double N = (double)BATCH * 936.0;
        double m = st0[0] / N;
        double var = st0[1] / N - m * m;
        double a = (double)g0[0] / sqrt(var + 1e-5);
        sa_s = (float)a;
        sc_s = (float)((double)b0[0] - m * a);
    }
    __syncthreads();
    float ls[8], lq[8];
#pragma unroll
    for (int o = 0; o < 8; o++) { ls[o] = 0.f; lq[o] = 0.f; }
    if (tid < 117) {
        float oc = bc[tid];
        for (int k = 0; k < 50; k++) oc = fmaf(embs[k], Wc[tid * 50 + k], oc);
        float h[9];
#pragma unroll
        for (int c = 0; c < 8; c++)
            h[c] = lrelu(fmaf(oi[(size_t)b * 936 + c * 117 + tid], sa_s, sc_s));
        h[8] = oc;
        float vn[8];
#pragma unroll
        for (int o = 0; o < 8; o++) {
            float a2 = 0.f;
#pragma unroll
            for (int c = 0; c < 9; c++) a2 = fmaf(W1s[o * 9 + c], h[c], a2);
            vn[o] = a2;
        }
        float* dp = v1 + ((size_t)b * 117 + tid) * 8;
        *(float4*)dp = make_float4(vn[0], vn[1], vn[2], vn[3]);
        *(float4*)(dp + 4) = make_float4(vn[4], vn[5], vn[6], vn[7]);
#pragma unroll
        for (int o = 0; o < 8; o++) vs[tid][o] = vn[o];
    }
    __syncthreads();
    if (tid < 117) {
        float csv = colsum1[tid];
        float4 bdv = band1[tid];
#pragma unroll
        for (int o = 0; o < 8; o++) {
            float v0 = vs[tid][o];
            ls[o] = fmaf(csv, v0, ls[o]);
            float t = bdv.x * v0;
            if (tid + 1 < 117) t = fmaf(bdv.y, vs[tid + 1][o], t);
            if (tid + 2 < 117) t = fmaf(bdv.z, vs[tid + 2][o], t);
            if (tid + 3 < 117) t = fmaf(bdv.w, vs[tid + 3][o], t);
            lq[o] = fmaf(v0, t, lq[o]);
        }
    }
#pragma unroll
    for (int o = 0; o < 8; o++)
        for (int off = 32; off > 0; off >>= 1) {
            ls[o] += __shfl_down(ls[o], off, 64);
            lq[o] += __shfl_down(lq[o], off, 64);
        }
    int wave = tid >> 6, lane = tid & 63;
    if (lane == 0)
#pragma unroll
        for (int o = 0; o < 8; o++) { red[wave][o] = ls[o]; red[wave][8 + o] = lq[o]; }
    __syncthreads();
    if (tid < 16)
        atomicAdd(&z1out[(b & 63) * 16 + tid], (double)(red[0][tid] + red[1][tid]));
}

// --------------------------------------------------- unified stage kernel ----
// Stage s: LDS-stage the needed vin row-range (coalesced float4, full MLP),
// then bn_s+lrelu+W_{s+1} with all 4-tap gathers served from LDS.
// R6 lesson: global gathers + tight VGPR cap serialize into dependent
// load-use chains (VALU 12%, HBM 5%) — stage first, gather from LDS.
__global__ __launch_bounds__(256, 2) void k_stage(
    const float* __restrict__ vin, float* __restrict__ vout,
    const float* __restrict__ W, const float* __restrict__ g,
    const float* __restrict__ bb,
    const double* __restrict__ zin, double* __restrict__ zout,
    const float* __restrict__ colsum, const float4* __restrict__ band,
    const int* __restrict__ ti0, const float4* __restrict__ tw,
    int Lin, int Lout, int nchunk)
{
    __shared__ float Ws[64], aa[8], cc[8];
    __shared__ float vins[264][9];    // staged input rows [qlo..qhi], NQ<=262
    __shared__ float vs[JC + 3][9];
    __shared__ float red[4][16];
    int tid = threadIdx.x;
    if (tid < 64) Ws[tid] = W[tid];
    if (tid < 8) {
        double s = 0.0, q = 0.0;
        for (int k = 0; k < 64; k++) { s += zin[k * 16 + tid]; q += zin[k * 16 + 8 + tid]; }
        double N = (double)BATCH * (double)Lout;
        double m = s / N;
        double var = q / N - m * m;
        double a = (double)g[tid] / sqrt(var + 1e-5);
        aa[tid] = (float)a;
        cc[tid] = (float)((double)bb[tid] - m * a);
    }
    int b = blockIdx.x / nchunk, ch = blockIdx.x - b * nchunk;
    int j0 = ch * JC, j1 = min(j0 + JC, Lout), je = min(j1 + 3, Lout);
    int qlo = max(0, ti0[j0] - 1);
    int qhi = min(Lin - 1, ti0[je - 1] + 2);
    int NQ = qhi - qlo + 1;
    // stage vin[qlo..qhi] -> LDS (coalesced, independent)
    const float4* srcp = (const float4*)(vin + ((size_t)b * Lin + qlo) * 8);
    for (int f = tid; f < NQ * 2; f += 256) {
        float4 v = srcp[f];
        int q = f >> 1, hf = (f & 1) * 4;
        vins[q][hf + 0] = v.x; vins[q][hf + 1] = v.y;
        vins[q][hf + 2] = v.z; vins[q][hf + 3] = v.w;
    }
    __syncthreads();
    // phase A: upsample(from LDS) -> bn -> lrelu -> W -> vs (+ global write)
    for (int jj = tid; jj < je - j0; jj += 256) {
        int j = j0 + jj;
        int i0 = ti0[j];
        float4 w = tw[j];
        float wk[4] = {w.x, w.y, w.z, w.w};
        float z[8] = {0.f, 0.f, 0.f, 0.f, 0.f, 0.f, 0.f, 0.f};
#pragma unroll
        for (int k = 0; k < 4; k++) {
            int q = min(max(i0 - 1 + k, 0), Lin - 1) - qlo;
            const float* vp = vins[q];
#pragma unroll
            for (int c = 0; c < 8; c++) z[c] = fmaf(wk[k], vp[c], z[c]);
        }
        float h[8];
#pragma unroll
        for (int c = 0; c < 8; c++) h[c] = lrelu(fmaf(z[c], aa[c], cc[c]));
        float vn[8];
#pragma unroll
        for (int o = 0; o < 8; o++) {
            float a2 = 0.f;
#pragma unroll
            for (int c = 0; c < 8; c++) a2 = fmaf(Ws[o * 8 + c], h[c], a2);
            vn[o] = a2;
        }
        if (vout != nullptr && jj < j1 - j0) {
            float* dp = vout + ((size_t)b * Lout + j) * 8;
            *(float4*)dp = make_float4(vn[0], vn[1], vn[2], vn[3]);
            *(float4*)(dp + 4) = make_float4(vn[4], vn[5], vn[6], vn[7]);
        }
#pragma unroll
        for (int o = 0; o < 8; o++) vs[jj][o] = vn[o];
    }
    __syncthreads();
    // phase B: banded stats for z_{s+1}
    float ls[8], lq[8];
#pragma unroll
    for (int o = 0; o < 8; o++) { ls[o] = 0.f; lq[o] = 0.f; }
    int nst = j1 - j0, ne = je - j0;
    for (int jj = tid; jj < nst; jj += 256) {
        int p = j0 + jj;
        float csv = colsum[p];
        float4 bdv = band[p];
#pragma unroll
        for (int o = 0; o < 8; o++) {
            float v0 = vs[jj][o];
            ls[o] = fmaf(csv, v0, ls[o]);
            float t = bdv.x * v0;
            if (jj + 1 < ne) t = fmaf(bdv.y, vs[jj + 1][o], t);
            if (jj + 2 < ne) t = fmaf(bdv.z, vs[jj + 2][o], t);
            if (jj + 3 < ne) t = fmaf(bdv.w, vs[jj + 3][o], t);
            lq[o] = fmaf(v0, t, lq[o]);
        }
    }
#pragma unroll
    for (int o = 0; o < 8; o++)
        for (int off = 32; off > 0; off >>= 1) {
            ls[o] += __shfl_down(ls[o], off, 64);
            lq[o] += __shfl_down(lq[o], off, 64);
        }
    int wave = tid >> 6, lane = tid & 63;
    if (lane == 0)
#pragma unroll
        for (int o = 0; o < 8; o++) { red[wave][o] = ls[o]; red[wave][8 + o] = lq[o]; }
    __syncthreads();
    if (tid < 16) {
        float v = red[0][tid] + red[1][tid] + red[2][tid] + red[3][tid];
        atomicAdd(&zout[(blockIdx.x & 63) * 16 + tid], (double)v);
    }
}

// ----------------- final fused kernel: v4(LDS) -> h4 -> v5(LDS) -> out ----
__global__ __launch_bounds__(256, 2) void k_final(
    const float* __restrict__ v4, float* __restrict__ out,
    const float* __restrict__ W5, const float* __restrict__ w6,
    const float* __restrict__ g4, const float* __restrict__ b4,
    const float* __restrict__ g5, const float* __restrict__ b5,
    const double* __restrict__ z4st, const double* __restrict__ z5st,
    const int* __restrict__ ti04, const float4* __restrict__ tw4,
    const int* __restrict__ ti05, const float4* __restrict__ tw5)
{
    __shared__ float W5s[64], w6s[8], a4[8], c4[8], a5[8], c5[8];
    __shared__ float v4s[140][9];     // staged v4 q-range, NQ<=135
    __shared__ float v5s[272][9];
    int tid = threadIdx.x;
    if (tid < 64) W5s[tid] = W5[tid];
    if (tid < 8) {
        w6s[tid] = w6[tid];
        double s = 0.0, q = 0.0;
        for (int k = 0; k < 64; k++) { s += z4st[k * 16 + tid]; q += z4st[k * 16 + 8 + tid]; }
        double N4 = (double)BATCH * (double)L4;
        double m = s / N4;
        double var = q / N4 - m * m;
        double a = (double)g4[tid] / sqrt(var + 1e-5);
        a4[tid] = (float)a;
        c4[tid] = (float)((double)b4[tid] - m * a);
        s = 0.0; q = 0.0;
        for (int k = 0; k < 64; k++) { s += z5st[k * 16 + tid]; q += z5st[k * 16 + 8 + tid]; }
        double N5 = (double)BATCH * (double)L5;
        m = s / N5;
        var = q / N5 - m * m;
        a = (double)g5[tid] / sqrt(var + 1e-5);
        a5[tid] = (float)a;
        c5[tid] = (float)((double)b5[tid] - m * a);
    }
    int b = blockIdx.x >> 3, ch = blockIdx.x & 7;
    int j0 = ch * JC, j1 = min(j0 + JC, L5);
    int plo = max(0, ti05[j0] - 1);
    int phi = min(L4 - 1, ti05[j1 - 1] + 2);
    int NP = phi - plo + 1;
    int qlo = max(0, ti04[plo] - 1);
    int qhi = min(L3 - 1, ti04[phi] + 2);
    int NQ = qhi - qlo + 1;
    // stage v4[qlo..qhi] -> LDS (coalesced, independent)
    const float4* srcp = (const float4*)(v4 + ((size_t)b * L3 + qlo) * 8);
    for (int f = tid; f < NQ * 2; f += 256) {
        float4 v = srcp[f];
        int q = f >> 1, hf = (f & 1) * 4;
        v4s[q][hf + 0] = v.x; v4s[q][hf + 1] = v.y;
        v4s[q][hf + 2] = v.z; v4s[q][hf + 3] = v.w;
    }
    __syncthreads();
    // phase A: v5 for p-range from LDS v4
    for (int pp = tid; pp < NP; pp += 256) {
        int p = plo + pp;
        int i0 = ti04[p];
        float4 w = tw4[p];
        float wk[4] = {w.x, w.y, w.z, w.w};
        float z[8] = {0.f, 0.f, 0.f, 0.f, 0.f, 0.f, 0.f, 0.f};
#pragma unroll
        for (int k = 0; k < 4; k++) {
            int q = min(max(i0 - 1 + k, 0), L3 - 1) - qlo;
            const float* vp = v4s[q];
#pragma unroll
            for (int c = 0; c < 8; c++) z[c] = fmaf(wk[k], vp[c], z[c]);
        }
        float h[8];
#pragma unroll
        for (int c = 0; c < 8; c++) h[c] = lrelu(fmaf(z[c], a4[c], c4[c]));
#pragma unroll
        for (int o = 0; o < 8; o++) {
            float a2 = 0.f;
#pragma unroll
            for (int c = 0; c < 8; c++) a2 = fmaf(W5s[o * 8 + c], h[c], a2);
            v5s[pp][o] = a2;
        }
    }
    __syncthreads();
    // phase B: upsample v5 -> bn5 -> lrelu -> dot w6 -> out
    for (int jj = tid; jj < j1 - j0; jj += 256) {
        int j = j0 + jj;
        int i0 = ti05[j];
        float4 w = tw5[j];
        float wk[4] = {w.x, w.y, w.z, w.w};
        float z[8] = {0.f, 0.f, 0.f, 0.f, 0.f, 0.f, 0.f, 0.f};
#pragma unroll
        for (int k = 0; k < 4; k++) {
            int pp = min(max(i0 - 1 + k, 0), L4 - 1) - plo;
            const float* vp = v5s[pp];
#pragma unroll
            for (int o = 0; o < 8; o++) z[o] = fmaf(wk[k], vp[o], z[o]);
        }
        float r = 0.f;
#pragma unroll
        for (int o = 0; o < 8; o++)
            r = fmaf(w6s[o], lrelu(fmaf(z[o], a5[o], c5[o])), r);
        out[(size_t)b * L5 + j] = r;
    }
}

// ---------------------------------------------------------------- launch ----
extern "C" void kernel_launch(void* const* d_in, const int* in_sizes, int n_in,
                              void* d_out, int out_size, void* d_ws, size_t ws_size,
                              hipStream_t stream)
{
    const float* x   = (const float*)d_in[0];
    const int*   y   = (const int*)d_in[1];
    const float* emb = (const float*)d_in[2];
    const float* Wc  = (const float*)d_in[3];
    const float* bc  = (const float*)d_in[4];
    const float* Wi  = (const float*)d_in[5];
    const float* bi  = (const float*)d_in[6];
    const float* g0  = (const float*)d_in[7];
    const float* b0  = (const float*)d_in[8];
    const float* w1  = (const float*)d_in[9];
    const float* w2  = (const float*)d_in[10];
    const float* w3  = (const float*)d_in[11];
    const float* w4  = (const float*)d_in[12];
    const float* w5  = (const float*)d_in[13];
    const float* w6  = (const float*)d_in[14];
    const float* g1  = (const float*)d_in[15];
    const float* b1  = (const float*)d_in[16];
    const float* g2  = (const float*)d_in[17];
    const float* b2  = (const float*)d_in[18];
    const float* g3  = (const float*)d_in[19];
    const float* b3  = (const float*)d_in[20];
    const float* g4  = (const float*)d_in[21];
    const float* b4  = (const float*)d_in[22];
    const float* g5  = (const float*)d_in[23];
    const float* b5  = (const float*)d_in[24];
    float* out = (float*)d_out;

    char* ws = (char*)d_ws;
    size_t off = 0;
    auto alloc = [&](size_t bytes) {
        size_t r = off;
        off += (bytes + 255) & ~(size_t)255;
        return r;
    };
    double* stats  = (double*)(ws + alloc(NSTATS * sizeof(double)));
    int*    ti0    = (int*)(ws + alloc((size_t)NTAB * sizeof(int)));
    float4* tw     = (float4*)(ws + alloc((size_t)NTAB * sizeof(float4)));
    float*  colsum = (float*)(ws + alloc((size_t)NBT * sizeof(float)));
    float4* band   = (float4*)(ws + alloc((size_t)NBT * sizeof(float4)));
    float*  oi     = (float*)(ws + alloc((size_t)BATCH * 936 * 4));
    float*  bufA   = (float*)(ws + alloc((size_t)BATCH * L2 * 8 * 4));   // v1 / v3
    float*  bufB   = (float*)(ws + alloc((size_t)BATCH * L3 * 8 * 4));   // v2 / v4

    double* st0  = stats;
    double* zst1 = stats + 16;
    double* zst2 = stats + 16 + 1024;
    double* zst3 = stats + 16 + 2048;
    double* zst4 = stats + 16 + 3072;
    double* zst5 = stats + 16 + 4096;

    const int u1 = 0, u2 = L1, u3 = L1 + L2, u4 = L1 + L2 + L3, u5 = L1 + L2 + L3 + L4;
    const int t1 = 0, t2 = L0, t3 = L0 + L1, t4 = L0 + L1 + L2, t5 = L0 + L1 + L2 + L3;

    float* v1 = bufA;
    float* v2 = bufB;
    float* v3 = bufA;
    float* v4 = bufB;

    k_setup<<<5, 256, 0, stream>>>(stats, ti0, tw);
    k_setup2<<<5, 256, 0, stream>>>(colsum, band);
    k0a<<<dim3(8, 64), 256, 0, stream>>>(x, Wi, bi, oi, st0);
    k0b<<<BATCH, 128, 0, stream>>>(oi, emb, y, Wc, bc, g0, b0, w1, st0, zst1,
                                   colsum + t1, band + t1, v1);
    // s1: v1 -> v2  (bn1, W2, z2 stats)
    k_stage<<<BATCH, 256, 0, stream>>>(v1, v2, w2, g1, b1, zst1, zst2,
                                       colsum + t2, band + t2, ti0 + u1, tw + u1, L0, L1, 1);
    // s2: v2 -> v3  (bn2, W3, z3 stats)
    k_stage<<<BATCH, 256, 0, stream>>>(v2, v3, w3, g2, b2, zst2, zst3,
                                       colsum + t3, band + t3, ti0 + u2, tw + u2, L1, L2, 1);
    // s3: v3 -> v4  (bn3, W4, z4 stats)
    k_stage<<<BATCH * 2, 256, 0, stream>>>(v3, v4, w4, g3, b3, zst3, zst4,
                                           colsum + t4, band + t4, ti0 + u3, tw + u3, L2, L3, 2);
    // s4: v4 -> (transient v5), z5 stats only
    k_stage<<<BATCH * 4, 256, 0, stream>>>(v4, nullptr, w5, g4, b4, zst4, zst5,
                                           colsum + t5, band + t5, ti0 + u4, tw + u4, L3, L4, 4);
    // s5: v4 -> h4 -> v5 -> h5 -> out
    k_final<<<BATCH * 8, 256, 0, stream>>>(v4, out, w5, w6, g4, b4, g5, b5, zst4, zst5,
                                           ti0 + u4, tw + u4, ti0 + u5, tw + u5);
}

// Round 9
// 858.250 us; speedup vs baseline: 1.8702x; 1.4275x over previous
//
#include <hip/hip_runtime.h>
#include <math.h>

#define BATCH 4096
#define L0 117
#define L1 234
#define L2 468
#define L3 937
#define L4 1875
#define L5 3750
#define JC 512
#define NTAB (L1 + L2 + L3 + L4 + L5)          // 7264 upsample-table entries
#define NBT  (L0 + L1 + L2 + L3 + L4)          // 3631 band-table entries
#define NSTATS (16 + 5 * 64 * 16)              // stats0 + 5 stages x 64 buckets x 16

static __device__ __forceinline__ float lrelu(float v) { return v >= 0.f ? v : 0.2f * v; }

// ---------------------------------------------------------------- setup ----
__global__ void k_setup(double* __restrict__ stats, int* __restrict__ ti0,
                        float4* __restrict__ tw)
{
    int s = blockIdx.x;
    if (s == 0)
        for (int i = threadIdx.x; i < NSTATS; i += blockDim.x) stats[i] = 0.0;
    const int Lin[5]  = {L0, L1, L2, L3, L4};
    const int Lout[5] = {L1, L2, L3, L4, L5};
    const int Uoff[5] = {0, L1, L1 + L2, L1 + L2 + L3, L1 + L2 + L3 + L4};
    int li = Lin[s], lo = Lout[s], off = Uoff[s];
    float scale = (float)((double)li / (double)lo);
    const float A = -0.75f;
    for (int j = threadIdx.x; j < lo; j += blockDim.x) {
        float src = ((float)j + 0.5f) * scale - 0.5f;
        float fi = floorf(src);
        float t = src - fi;
        float u;
        float4 w;
        u = t + 1.f; w.x = ((A * u - 5.f * A) * u + 8.f * A) * u - 4.f * A;
        u = t;       w.y = ((A + 2.f) * u - (A + 3.f)) * u * u + 1.f;
        u = 1.f - t; w.z = ((A + 2.f) * u - (A + 3.f)) * u * u + 1.f;
        u = 2.f - t; w.w = ((A * u - 5.f * A) * u + 8.f * A) * u - 4.f * A;
        ti0[off + j] = (int)fi;
        tw[off + j] = w;
    }
}

// Band tables: exact Gram identity for upsample stats (see R2 notes).
__global__ __launch_bounds__(256) void k_setup2(float* __restrict__ colsum,
                                                float4* __restrict__ band)
{
    __shared__ float cs[1880];
    __shared__ float bd[1880][4];
    int s = blockIdx.x;
    const int Lin[5]  = {L0, L1, L2, L3, L4};
    const int Lout[5] = {L1, L2, L3, L4, L5};
    const int Toff[5] = {0, L0, L0 + L1, L0 + L1 + L2, L0 + L1 + L2 + L3};
    int li = Lin[s], lo = Lout[s], off = Toff[s];
    for (int i = threadIdx.x; i < li; i += 256) {
        cs[i] = 0.f; bd[i][0] = 0.f; bd[i][1] = 0.f; bd[i][2] = 0.f; bd[i][3] = 0.f;
    }
    __syncthreads();
    float scale = (float)((double)li / (double)lo);
    const float A = -0.75f;
    for (int j = threadIdx.x; j < lo; j += 256) {
        float src = ((float)j + 0.5f) * scale - 0.5f;
        float fi = floorf(src);
        float t = src - fi;
        int i0 = (int)fi;
        float u, w[4];
        u = t + 1.f; w[0] = ((A * u - 5.f * A) * u + 8.f * A) * u - 4.f * A;
        u = t;       w[1] = ((A + 2.f) * u - (A + 3.f)) * u * u + 1.f;
        u = 1.f - t; w[2] = ((A + 2.f) * u - (A + 3.f)) * u * u + 1.f;
        u = 2.f - t; w[3] = ((A * u - 5.f * A) * u + 8.f * A) * u - 4.f * A;
        int q[4];
#pragma unroll
        for (int k = 0; k < 4; k++) q[k] = min(max(i0 - 1 + k, 0), li - 1);
#pragma unroll
        for (int k = 0; k < 4; k++) atomicAdd(&cs[q[k]], w[k]);
#pragma unroll
        for (int k = 0; k < 4; k++)
#pragma unroll
            for (int l = 0; l < 4; l++) {
                int qa = q[k], qb = q[l];
                int qm = min(qa, qb), d = abs(qa - qb);
                atomicAdd(&bd[qm][d], w[k] * w[l]);
            }
    }
    __syncthreads();
    for (int i = threadIdx.x; i < li; i += 256) {
        colsum[off + i] = cs[i];
        band[off + i] = make_float4(bd[i][0], bd[i][1], bd[i][2], bd[i][3]);
    }
}

// ------------- stats buckets -> (a,c) coefficients, computed ONCE ----------
// R8 lesson: every block re-reducing 64x16 doubles was ~1-2K cy of fixed
// overhead x ~50K blocks. Same double math as before -> bit-identical.
__global__ void k_coef(const double* __restrict__ zb, const float* __restrict__ g,
                       const float* __restrict__ bb, double N,
                       float* __restrict__ coef)
{
    __shared__ double col[16];
    int tid = threadIdx.x;
    if (tid < 16) {
        double s = 0.0;
        for (int k = 0; k < 64; k++) s += zb[k * 16 + tid];
        col[tid] = s;
    }
    __syncthreads();
    if (tid < 8) {
        double m = col[tid] / N;
        double var = col[8 + tid] / N - m * m;
        double a = (double)g[tid] / sqrt(var + 1e-5);
        coef[tid] = (float)a;
        coef[8 + tid] = (float)((double)bb[tid] - m * a);
    }
}

// ------------------------------------------------- input GEMM + bn0 stats ----
__global__ __launch_bounds__(256) void k0a(const float* __restrict__ x,
                                           const float* __restrict__ Wi,
                                           const float* __restrict__ bi,
                                           float* __restrict__ oi,
                                           double* __restrict__ stats)
{
    __shared__ float As[32][68];
    __shared__ float Bs[32][132];
    __shared__ float red[512];
    int m0 = blockIdx.y * 64;
    int n0 = blockIdx.x * 128;
    int tid = threadIdx.x;
    int tm = tid >> 4, tn = tid & 15;
    float acc[4][8];
#pragma unroll
    for (int r = 0; r < 4; r++)
#pragma unroll
        for (int c = 0; c < 8; c++) acc[r][c] = 0.f;

    for (int k0 = 0; k0 < 160; k0 += 32) {
        for (int e = tid; e < 64 * 32; e += 256) {
            int m = e >> 5, k = e & 31;
            As[k][m] = x[(size_t)(m0 + m) * 160 + k0 + k];
        }
        for (int e = tid; e < 128 * 32; e += 256) {
            int n = e >> 5, k = e & 31;
            int row = n0 + n;
            Bs[k][n] = (row < 936) ? Wi[(size_t)row * 160 + k0 + k] : 0.f;
        }
        __syncthreads();
#pragma unroll
        for (int k = 0; k < 32; k++) {
            float4 av = *(const float4*)&As[k][tm * 4];
            float4 bv0 = *(const float4*)&Bs[k][tn * 8];
            float4 bv1 = *(const float4*)&Bs[k][tn * 8 + 4];
            float a[4] = {av.x, av.y, av.z, av.w};
            float b[8] = {bv0.x, bv0.y, bv0.z, bv0.w, bv1.x, bv1.y, bv1.z, bv1.w};
#pragma unroll
            for (int r = 0; r < 4; r++)
#pragma unroll
                for (int c = 0; c < 8; c++) acc[r][c] = fmaf(a[r], b[c], acc[r][c]);
        }
        __syncthreads();
    }
    float lsum = 0.f, lsq = 0.f;
#pragma unroll
    for (int r = 0; r < 4; r++) {
        int row = m0 + tm * 4 + r;
        int col = n0 + tn * 8;
        float vals[8];
#pragma unroll
        for (int c = 0; c < 8; c++) {
            float v = (col + c < 936) ? acc[r][c] + bi[col + c] : 0.f;
            vals[c] = v;
            lsum += v;
            lsq += v * v;
        }
        if (col + 7 < 936) {
            *(float4*)&oi[(size_t)row * 936 + col] = make_float4(vals[0], vals[1], vals[2], vals[3]);
            *(float4*)&oi[(size_t)row * 936 + col + 4] = make_float4(vals[4], vals[5], vals[6], vals[7]);
        } else {
            for (int c = 0; c < 8; c++)
                if (col + c < 936) oi[(size_t)row * 936 + col + c] = vals[c];
        }
    }
    red[tid] = lsum;
    red[256 + tid] = lsq;
    __syncthreads();
    for (int st = 128; st > 0; st >>= 1) {
        if (tid < st) { red[tid] += red[tid + st]; red[256 + tid] += red[256 + tid + st]; }
        __syncthreads();
    }
    if (tid == 0) {
        atomicAdd(&stats[0], (double)red[0]);
        atomicAdd(&stats[1], (double)red[256]);
    }
}

// ------------- bn0 apply + class branch -> v1 = W1·h0, + z1 band stats ----
__global__ __launch_bounds__(128) void k0b(const float* __restrict__ oi,
                                           const float* __restrict__ emb,
                                           const int* __restrict__ y,
                                           const float* __restrict__ Wc,
                                           const float* __restrict__ bc,
                                           const float* __restrict__ g0,
                                           const float* __restrict__ b0,
                                           const float* __restrict__ w1,
                                           const double* __restrict__ st0,
                                           double* __restrict__ z1out,
                                           const float* __restrict__ colsum1,
                                           const float4* __restrict__ band1,
                                           float* __restrict__ v1)
{
    __shared__ float embs[50], W1s[72];
    __shared__ float sa_s, sc_s;
    __shared__ float vs[117][9];
    __shared__ float red[2][16];
    int b = blockIdx.x, tid = threadIdx.x;
    if (tid < 50) embs[tid] = emb[y[b] * 50 + tid];
    else if (tid < 122) W1s[tid - 50] = w1[tid - 50];
    else if (tid == 122) {
        double N = (double)BATCH * 936.0;
        double m = st0[0] / N;
        double var = st0[1] / N - m * m;
        double a = (double)g0[0] / sqrt(var + 1e-5);
        sa_s = (float)a;
        sc_s = (float)((double)b0[0] - m * a);
    }
    __syncthreads();
    float ls[8], lq[8];
#pragma unroll
    for (int o = 0; o < 8; o++) { ls[o] = 0.f; lq[o] = 0.f; }
    if (tid < 117) {
        float oc = bc[tid];
        for (int k = 0; k < 50; k++) oc = fmaf(embs[k], Wc[tid * 50 + k], oc);
        float h[9];
#pragma unroll
        for (int c = 0; c < 8; c++)
            h[c] = lrelu(fmaf(oi[(size_t)b * 936 + c * 117 + tid], sa_s, sc_s));
        h[8] = oc;
        float vn[8];
#pragma unroll
        for (int o = 0; o < 8; o++) {
            float a2 = 0.f;
#pragma unroll
            for (int c = 0; c < 9; c++) a2 = fmaf(W1s[o * 9 + c], h[c], a2);
            vn[o] = a2;
        }
        float* dp = v1 + ((size_t)b * 117 + tid) * 8;
        *(float4*)dp = make_float4(vn[0], vn[1], vn[2], vn[3]);
        *(float4*)(dp + 4) = make_float4(vn[4], vn[5], vn[6], vn[7]);
#pragma unroll
        for (int o = 0; o < 8; o++) vs[tid][o] = vn[o];
    }
    __syncthreads();
    if (tid < 117) {
        float csv = colsum1[tid];
        float4 bdv = band1[tid];
#pragma unroll
        for (int o = 0; o < 8; o++) {
            float v0 = vs[tid][o];
            ls[o] = fmaf(csv, v0, ls[o]);
            float t = bdv.x * v0;
            if (tid + 1 < 117) t = fmaf(bdv.y, vs[tid + 1][o], t);
            if (tid + 2 < 117) t = fmaf(bdv.z, vs[tid + 2][o], t);
            if (tid + 3 < 117) t = fmaf(bdv.w, vs[tid + 3][o], t);
            lq[o] = fmaf(v0, t, lq[o]);
        }
    }
#pragma unroll
    for (int o = 0; o < 8; o++)
        for (int off = 32; off > 0; off >>= 1) {
            ls[o] += __shfl_down(ls[o], off, 64);
            lq[o] += __shfl_down(lq[o], off, 64);
        }
    int wave = tid >> 6, lane = tid & 63;
    if (lane == 0)
#pragma unroll
        for (int o = 0; o < 8; o++) { red[wave][o] = ls[o]; red[wave][8 + o] = lq[o]; }
    __syncthreads();
    if (tid < 16)
        atomicAdd(&z1out[(b & 63) * 16 + tid], (double)(red[0][tid] + red[1][tid]));
}

// --------------------------------------------------- unified stage kernel ----
// ONE BLOCK PER BATCH ELEMENT (R8 lesson: per-block fixed costs dominated at
// 50K tiny blocks). Stage full vin row once; loop chunks internally.
template <int LIN, int LOUT>
__global__ __launch_bounds__(256, 2) void k_stage(
    const float* __restrict__ vin, float* __restrict__ vout,
    const float* __restrict__ W, const float* __restrict__ coef,
    double* __restrict__ zout,
    const float* __restrict__ colsum, const float4* __restrict__ band,
    const int* __restrict__ ti0, const float4* __restrict__ tw)
{
    constexpr int NCH = (LOUT + JC - 1) / JC;
    constexpr int VSN = (LOUT < JC ? LOUT : JC) + 3;
    __shared__ float Ws[64], aa[8], cc[8];
    __shared__ float vins[LIN][9];
    __shared__ float vs[VSN][9];
    __shared__ float red[4][16];
    int tid = threadIdx.x;
    if (tid < 64) Ws[tid] = W[tid];
    if (tid < 8) { aa[tid] = coef[tid]; cc[tid] = coef[8 + tid]; }
    int b = blockIdx.x;
    // stage full vin row -> LDS (coalesced, independent)
    const float4* srcp = (const float4*)(vin + (size_t)b * LIN * 8);
    for (int f = tid; f < LIN * 2; f += 256) {
        float4 v = srcp[f];
        int q = f >> 1, hf = (f & 1) * 4;
        vins[q][hf + 0] = v.x; vins[q][hf + 1] = v.y;
        vins[q][hf + 2] = v.z; vins[q][hf + 3] = v.w;
    }
    float ls[8], lq[8];
#pragma unroll
    for (int o = 0; o < 8; o++) { ls[o] = 0.f; lq[o] = 0.f; }
    __syncthreads();

    for (int ch = 0; ch < NCH; ch++) {
        int j0 = ch * JC, j1 = min(j0 + JC, LOUT), je = min(j1 + 3, LOUT);
        // phase A: upsample(LDS) -> bn -> lrelu -> W -> vs (+ global write)
        for (int jj = tid; jj < je - j0; jj += 256) {
            int j = j0 + jj;
            int i0 = ti0[j];
            float4 w = tw[j];
            float wk[4] = {w.x, w.y, w.z, w.w};
            float z[8] = {0.f, 0.f, 0.f, 0.f, 0.f, 0.f, 0.f, 0.f};
#pragma unroll
            for (int k = 0; k < 4; k++) {
                int q = min(max(i0 - 1 + k, 0), LIN - 1);
                const float* vp = vins[q];
#pragma unroll
                for (int c = 0; c < 8; c++) z[c] = fmaf(wk[k], vp[c], z[c]);
            }
            float h[8];
#pragma unroll
            for (int c = 0; c < 8; c++) h[c] = lrelu(fmaf(z[c], aa[c], cc[c]));
            float vn[8];
#pragma unroll
            for (int o = 0; o < 8; o++) {
                float a2 = 0.f;
#pragma unroll
                for (int c = 0; c < 8; c++) a2 = fmaf(Ws[o * 8 + c], h[c], a2);
                vn[o] = a2;
            }
            if (vout != nullptr && jj < j1 - j0) {
                float* dp = vout + ((size_t)b * LOUT + j) * 8;
                *(float4*)dp = make_float4(vn[0], vn[1], vn[2], vn[3]);
                *(float4*)(dp + 4) = make_float4(vn[4], vn[5], vn[6], vn[7]);
            }
#pragma unroll
            for (int o = 0; o < 8; o++) vs[jj][o] = vn[o];
        }
        __syncthreads();
        // phase B: banded stats for z_{s+1}
        int nst = j1 - j0, ne = je - j0;
        for (int jj = tid; jj < nst; jj += 256) {
            int p = j0 + jj;
            float csv = colsum[p];
            float4 bdv = band[p];
#pragma unroll
            for (int o = 0; o < 8; o++) {
                float v0 = vs[jj][o];
                ls[o] = fmaf(csv, v0, ls[o]);
                float t = bdv.x * v0;
                if (jj + 1 < ne) t = fmaf(bdv.y, vs[jj + 1][o], t);
                if (jj + 2 < ne) t = fmaf(bdv.z, vs[jj + 2][o], t);
                if (jj + 3 < ne) t = fmaf(bdv.w, vs[jj + 3][o], t);
                lq[o] = fmaf(v0, t, lq[o]);
            }
        }
        __syncthreads();   // vs reused next chunk
    }

#pragma unroll
    for (int o = 0; o < 8; o++)
        for (int off = 32; off > 0; off >>= 1) {
            ls[o] += __shfl_down(ls[o], off, 64);
            lq[o] += __shfl_down(lq[o], off, 64);
        }
    int wave = tid >> 6, lane = tid & 63;
    if (lane == 0)
#pragma unroll
        for (int o = 0; o < 8; o++) { red[wave][o] = ls[o]; red[wave][8 + o] = lq[o]; }
    __syncthreads();
    if (tid < 16) {
        float v = red[0][tid] + red[1][tid] + red[2][tid] + red[3][tid];
        atomicAdd(&zout[(blockIdx.x & 63) * 16 + tid], (double)v);
    }
}

// ----------------- final: v4(LDS full row) -> h4 -> v5(LDS) -> out ---------
// One block per batch element; 8 internal chunks.
__global__ __launch_bounds__(256, 2) void k_final(
    const float* __restrict__ v4, float* __restrict__ out,
    const float* __restrict__ W5, const float* __restrict__ w6,
    const float* __restrict__ coef4, const float* __restrict__ coef5,
    const int* __restrict__ ti04, const float4* __restrict__ tw4,
    const int* __restrict__ ti05, const float4* __restrict__ tw5)
{
    __shared__ float W5s[64], w6s[8], a4[8], c4[8], a5[8], c5[8];
    __shared__ float v4s[L3][9];      // full v4 row, 33.7 KB
    __shared__ float v5s[264][9];     // per-chunk p-range
    int tid = threadIdx.x;
    if (tid < 64) W5s[tid] = W5[tid];
    if (tid < 8) {
        w6s[tid] = w6[tid];
        a4[tid] = coef4[tid]; c4[tid] = coef4[8 + tid];
        a5[tid] = coef5[tid]; c5[tid] = coef5[8 + tid];
    }
    int b = blockIdx.x;
    const float4* srcp = (const float4*)(v4 + (size_t)b * L3 * 8);
    for (int f = tid; f < L3 * 2; f += 256) {
        float4 v = srcp[f];
        int q = f >> 1, hf = (f & 1) * 4;
        v4s[q][hf + 0] = v.x; v4s[q][hf + 1] = v.y;
        v4s[q][hf + 2] = v.z; v4s[q][hf + 3] = v.w;
    }
    __syncthreads();

    for (int ch = 0; ch < 8; ch++) {
        int j0 = ch * JC, j1 = min(j0 + JC, L5);
        int plo = max(0, ti05[j0] - 1);
        int phi = min(L4 - 1, ti05[j1 - 1] + 2);
        int NP = phi - plo + 1;
        // phase A: v5 for p-range from LDS v4
        for (int pp = tid; pp < NP; pp += 256) {
            int p = plo + pp;
            int i0 = ti04[p];
            float4 w = tw4[p];
            float wk[4] = {w.x, w.y, w.z, w.w};
            float z[8] = {0.f, 0.f, 0.f, 0.f, 0.f, 0.f, 0.f, 0.f};
#pragma unroll
            for (int k = 0; k < 4; k++) {
                int q = min(max(i0 - 1 + k, 0), L3 - 1);
                const float* vp = v4s[q];
#pragma unroll
                for (int c = 0; c < 8; c++) z[c] = fmaf(wk[k], vp[c], z[c]);
            }
            float h[8];
#pragma unroll
            for (int c = 0; c < 8; c++) h[c] = lrelu(fmaf(z[c], a4[c], c4[c]));
#pragma unroll
            for (int o = 0; o < 8; o++) {
                float a2 = 0.f;
#pragma unroll
                for (int c = 0; c < 8; c++) a2 = fmaf(W5s[o * 8 + c], h[c], a2);
                v5s[pp][o] = a2;
            }
        }
        __syncthreads();
        // phase B: upsample v5 -> bn5 -> lrelu -> dot w6 -> out
        for (int jj = tid; jj < j1 - j0; jj += 256) {
            int j = j0 + jj;
            int i0 = ti05[j];
            float4 w = tw5[j];
            float wk[4] = {w.x, w.y, w.z, w.w};
            float z[8] = {0.f, 0.f, 0.f, 0.f, 0.f, 0.f, 0.f, 0.f};
#pragma unroll
            for (int k = 0; k < 4; k++) {
                int pp = min(max(i0 - 1 + k, 0), L4 - 1) - plo;
                const float* vp = v5s[pp];
#pragma unroll
                for (int o = 0; o < 8; o++) z[o] = fmaf(wk[k], vp[o], z[o]);
            }
            float r = 0.f;
#pragma unroll
            for (int o = 0; o < 8; o++)
                r = fmaf(w6s[o], lrelu(fmaf(z[o], a5[o], c5[o])), r);
            out[(size_t)b * L5 + j] = r;
        }
        __syncthreads();   // v5s reused next chunk
    }
}

// ---------------------------------------------------------------- launch ----
extern "C" void kernel_launch(void* const* d_in, const int* in_sizes, int n_in,
                              void* d_out, int out_size, void* d_ws, size_t ws_size,
                              hipStream_t stream)
{
    const float* x   = (const float*)d_in[0];
    const int*   y   = (const int*)d_in[1];
    const float* emb = (const float*)d_in[2];
    const float* Wc  = (const float*)d_in[3];
    const float* bc  = (const float*)d_in[4];
    const float* Wi  = (const float*)d_in[5];
    const float* bi  = (const float*)d_in[6];
    const float* g0  = (const float*)d_in[7];
    const float* b0  = (const float*)d_in[8];
    const float* w1  = (const float*)d_in[9];
    const float* w2  = (const float*)d_in[10];
    const float* w3  = (const float*)d_in[11];
    const float* w4  = (const float*)d_in[12];
    const float* w5  = (const float*)d_in[13];
    const float* w6  = (const float*)d_in[14];
    const float* g1  = (const float*)d_in[15];
    const float* b1  = (const float*)d_in[16];
    const float* g2  = (const float*)d_in[17];
    const float* b2  = (const float*)d_in[18];
    const float* g3  = (const float*)d_in[19];
    const float* b3  = (const float*)d_in[20];
    const float* g4  = (const float*)d_in[21];
    const float* b4  = (const float*)d_in[22];
    const float* g5  = (const float*)d_in[23];
    const float* b5  = (const float*)d_in[24];
    float* out = (float*)d_out;

    char* ws = (char*)d_ws;
    size_t off = 0;
    auto alloc = [&](size_t bytes) {
        size_t r = off;
        off += (bytes + 255) & ~(size_t)255;
        return r;
    };
    double* stats  = (double*)(ws + alloc(NSTATS * sizeof(double)));
    float*  coefs  = (float*)(ws + alloc(5 * 16 * sizeof(float)));
    int*    ti0    = (int*)(ws + alloc((size_t)NTAB * sizeof(int)));
    float4* tw     = (float4*)(ws + alloc((size_t)NTAB * sizeof(float4)));
    float*  colsum = (float*)(ws + alloc((size_t)NBT * sizeof(float)));
    float4* band   = (float4*)(ws + alloc((size_t)NBT * sizeof(float4)));
    float*  oi     = (float*)(ws + alloc((size_t)BATCH * 936 * 4));
    float*  bufA   = (float*)(ws + alloc((size_t)BATCH * L2 * 8 * 4));   // v1 / v3
    float*  bufB   = (float*)(ws + alloc((size_t)BATCH * L3 * 8 * 4));   // v2 / v4

    double* st0  = stats;
    double* zst1 = stats + 16;
    double* zst2 = stats + 16 + 1024;
    double* zst3 = stats + 16 + 2048;
    double* zst4 = stats + 16 + 3072;
    double* zst5 = stats + 16 + 4096;
    float* coef1 = coefs +  0;
    float* coef2 = coefs + 16;
    float* coef3 = coefs + 32;
    float* coef4 = coefs + 48;
    float* coef5 = coefs + 64;

    const int u1 = 0, u2 = L1, u3 = L1 + L2, u4 = L1 + L2 + L3, u5 = L1 + L2 + L3 + L4;
    const int t1 = 0, t2 = L0, t3 = L0 + L1, t4 = L0 + L1 + L2, t5 = L0 + L1 + L2 + L3;

    float* v1 = bufA;
    float* v2 = bufB;
    float* v3 = bufA;
    float* v4 = bufB;

    k_setup<<<5, 256, 0, stream>>>(stats, ti0, tw);
    k_setup2<<<5, 256, 0, stream>>>(colsum, band);
    k0a<<<dim3(8, 64), 256, 0, stream>>>(x, Wi, bi, oi, st0);
    k0b<<<BATCH, 128, 0, stream>>>(oi, emb, y, Wc, bc, g0, b0, w1, st0, zst1,
                                   colsum + t1, band + t1, v1);
    k_coef<<<1, 64, 0, stream>>>(zst1, g1, b1, (double)BATCH * L1, coef1);
    // s1: v1 -> v2  (bn1, W2, z2 stats)
    k_stage<L0, L1><<<BATCH, 256, 0, stream>>>(v1, v2, w2, coef1, zst2,
                                               colsum + t2, band + t2, ti0 + u1, tw + u1);
    k_coef<<<1, 64, 0, stream>>>(zst2, g2, b2, (double)BATCH * L2, coef2);
    // s2: v2 -> v3  (bn2, W3, z3 stats)
    k_stage<L1, L2><<<BATCH, 256, 0, stream>>>(v2, v3, w3, coef2, zst3,
                                               colsum + t3, band + t3, ti0 + u2, tw + u2);
    k_coef<<<1, 64, 0, stream>>>(zst3, g3, b3, (double)BATCH * L3, coef3);
    // s3: v3 -> v4  (bn3, W4, z4 stats)
    k_stage<L2, L3><<<BATCH, 256, 0, stream>>>(v3, v4, w4, coef3, zst4,
                                               colsum + t4, band + t4, ti0 + u3, tw + u3);
    k_coef<<<1, 64, 0, stream>>>(zst4, g4, b4, (double)BATCH * L4, coef4);
    // s4: v4 -> (transient v5), z5 stats only
    k_stage<L3, L4><<<BATCH, 256, 0, stream>>>(v4, nullptr, w5, coef4, zst5,
                                               colsum + t5, band + t5, ti0 + u4, tw + u4);
    k_coef<<<1, 64, 0, stream>>>(zst5, g5, b5, (double)BATCH * L5, coef5);
    // s5: v4 -> h4 -> v5 -> h5 -> out
    k_final<<<BATCH, 256, 0, stream>>>(v4, out, w5, w6, coef4, coef5,
                                       ti0 + u4, tw + u4, ti0 + u5, tw + u5);
}

// Round 12
// 818.923 us; speedup vs baseline: 1.9601x; 1.0480x over previous
//
#include <hip/hip_runtime.h>
#include <math.h>

#define BATCH 4096
#define L0 117
#define L1 234
#define L2 468
#define L3 937
#define L4 1875
#define L5 3750
#define NBT  (L0 + L1 + L2 + L3 + L4)          // 3631 band-table entries
#define NSTATS (16 + 5 * 64 * 16)              // stats0 + 5 stages x 64 buckets x 16

static __device__ __forceinline__ float lrelu(float v) { return v >= 0.f ? v : 0.2f * v; }

// Inline bicubic taps: bit-identical formula/order to the original k_setup
// table build (R9 lesson: ti0[j]/tw[j] global loads were a dependent ~200cy
// L2 access at the head of EVERY iteration; ~20 VALU ops beat that).
static __device__ __forceinline__ void bicw(int j, float scale, int& i0, float* w)
{
    float src = ((float)j + 0.5f) * scale - 0.5f;
    float fi = floorf(src);
    float t = src - fi;
    const float A = -0.75f;
    float u;
    u = t + 1.f; w[0] = ((A * u - 5.f * A) * u + 8.f * A) * u - 4.f * A;
    u = t;       w[1] = ((A + 2.f) * u - (A + 3.f)) * u * u + 1.f;
    u = 1.f - t; w[2] = ((A + 2.f) * u - (A + 3.f)) * u * u + 1.f;
    u = 2.f - t; w[3] = ((A * u - 5.f * A) * u + 8.f * A) * u - 4.f * A;
    i0 = (int)fi;
}

// ---------------------------------------------------------------- setup ----
__global__ void k_setup(double* __restrict__ stats)
{
    for (int i = threadIdx.x; i < NSTATS; i += blockDim.x) stats[i] = 0.0;
}

// Band tables: exact Gram identity for upsample stats (see R2 notes).
__global__ __launch_bounds__(256) void k_setup2(float* __restrict__ colsum,
                                                float4* __restrict__ band)
{
    __shared__ float cs[1880];
    __shared__ float bd[1880][4];
    int s = blockIdx.x;
    const int Lin[5]  = {L0, L1, L2, L3, L4};
    const int Lout[5] = {L1, L2, L3, L4, L5};
    const int Toff[5] = {0, L0, L0 + L1, L0 + L1 + L2, L0 + L1 + L2 + L3};
    int li = Lin[s], lo = Lout[s], off = Toff[s];
    for (int i = threadIdx.x; i < li; i += 256) {
        cs[i] = 0.f; bd[i][0] = 0.f; bd[i][1] = 0.f; bd[i][2] = 0.f; bd[i][3] = 0.f;
    }
    __syncthreads();
    float scale = (float)((double)li / (double)lo);
    for (int j = threadIdx.x; j < lo; j += 256) {
        int i0;
        float w[4];
        bicw(j, scale, i0, w);
        int q[4];
#pragma unroll
        for (int k = 0; k < 4; k++) q[k] = min(max(i0 - 1 + k, 0), li - 1);
#pragma unroll
        for (int k = 0; k < 4; k++) atomicAdd(&cs[q[k]], w[k]);
#pragma unroll
        for (int k = 0; k < 4; k++)
#pragma unroll
            for (int l = 0; l < 4; l++) {
                int qa = q[k], qb = q[l];
                int qm = min(qa, qb), d = abs(qa - qb);
                atomicAdd(&bd[qm][d], w[k] * w[l]);
            }
    }
    __syncthreads();
    for (int i = threadIdx.x; i < li; i += 256) {
        colsum[off + i] = cs[i];
        band[off + i] = make_float4(bd[i][0], bd[i][1], bd[i][2], bd[i][3]);
    }
}

// ------------- stats buckets -> (a,c) coefficients, computed ONCE ----------
__global__ void k_coef(const double* __restrict__ zb, const float* __restrict__ g,
                       const float* __restrict__ bb, double N,
                       float* __restrict__ coef)
{
    __shared__ double col[16];
    int tid = threadIdx.x;
    if (tid < 16) {
        double s = 0.0;
        for (int k = 0; k < 64; k++) s += zb[k * 16 + tid];
        col[tid] = s;
    }
    __syncthreads();
    if (tid < 8) {
        double m = col[tid] / N;
        double var = col[8 + tid] / N - m * m;
        double a = (double)g[tid] / sqrt(var + 1e-5);
        coef[tid] = (float)a;
        coef[8 + tid] = (float)((double)bb[tid] - m * a);
    }
}

// ------------------------------------------------- input GEMM + bn0 stats ----
__global__ __launch_bounds__(256) void k0a(const float* __restrict__ x,
                                           const float* __restrict__ Wi,
                                           const float* __restrict__ bi,
                                           float* __restrict__ oi,
                                           double* __restrict__ stats)
{
    __shared__ float As[32][68];
    __shared__ float Bs[32][132];
    __shared__ float red[512];
    int m0 = blockIdx.y * 64;
    int n0 = blockIdx.x * 128;
    int tid = threadIdx.x;
    int tm = tid >> 4, tn = tid & 15;
    float acc[4][8];
#pragma unroll
    for (int r = 0; r < 4; r++)
#pragma unroll
        for (int c = 0; c < 8; c++) acc[r][c] = 0.f;

    for (int k0 = 0; k0 < 160; k0 += 32) {
        for (int e = tid; e < 64 * 32; e += 256) {
            int m = e >> 5, k = e & 31;
            As[k][m] = x[(size_t)(m0 + m) * 160 + k0 + k];
        }
        for (int e = tid; e < 128 * 32; e += 256) {
            int n = e >> 5, k = e & 31;
            int row = n0 + n;
            Bs[k][n] = (row < 936) ? Wi[(size_t)row * 160 + k0 + k] : 0.f;
        }
        __syncthreads();
#pragma unroll
        for (int k = 0; k < 32; k++) {
            float4 av = *(const float4*)&As[k][tm * 4];
            float4 bv0 = *(const float4*)&Bs[k][tn * 8];
            float4 bv1 = *(const float4*)&Bs[k][tn * 8 + 4];
            float a[4] = {av.x, av.y, av.z, av.w};
            float b[8] = {bv0.x, bv0.y, bv0.z, bv0.w, bv1.x, bv1.y, bv1.z, bv1.w};
#pragma unroll
            for (int r = 0; r < 4; r++)
#pragma unroll
                for (int c = 0; c < 8; c++) acc[r][c] = fmaf(a[r], b[c], acc[r][c]);
        }
        __syncthreads();
    }
    float lsum = 0.f, lsq = 0.f;
#pragma unroll
    for (int r = 0; r < 4; r++) {
        int row = m0 + tm * 4 + r;
        int col = n0 + tn * 8;
        float vals[8];
#pragma unroll
        for (int c = 0; c < 8; c++) {
            float v = (col + c < 936) ? acc[r][c] + bi[col + c] : 0.f;
            vals[c] = v;
            lsum += v;
            lsq += v * v;
        }
        if (col + 7 < 936) {
            *(float4*)&oi[(size_t)row * 936 + col] = make_float4(vals[0], vals[1], vals[2], vals[3]);
            *(float4*)&oi[(size_t)row * 936 + col + 4] = make_float4(vals[4], vals[5], vals[6], vals[7]);
        } else {
            for (int c = 0; c < 8; c++)
                if (col + c < 936) oi[(size_t)row * 936 + col + c] = vals[c];
        }
    }
    red[tid] = lsum;
    red[256 + tid] = lsq;
    __syncthreads();
    for (int st = 128; st > 0; st >>= 1) {
        if (tid < st) { red[tid] += red[tid + st]; red[256 + tid] += red[256 + tid + st]; }
        __syncthreads();
    }
    if (tid == 0) {
        atomicAdd(&stats[0], (double)red[0]);
        atomicAdd(&stats[1], (double)red[256]);
    }
}

// ------------- bn0 apply + class branch -> v1 = W1·h0, + z1 band stats ----
__global__ __launch_bounds__(128) void k0b(const float* __restrict__ oi,
                                           const float* __restrict__ emb,
                                           const int* __restrict__ y,
                                           const float* __restrict__ Wc,
                                           const float* __restrict__ bc,
                                           const float* __restrict__ g0,
                                           const float* __restrict__ b0,
                                           const float* __restrict__ w1,
                                           const double* __restrict__ st0,
                                           double* __restrict__ z1out,
                                           const float* __restrict__ colsum1,
                                           const float4* __restrict__ band1,
                                           float* __restrict__ v1)
{
    __shared__ float embs[50], W1s[72];
    __shared__ float sa_s, sc_s;
    __shared__ float vs[117][9];
    __shared__ float red[2][16];
    int b = blockIdx.x, tid = threadIdx.x;
    if (tid < 50) embs[tid] = emb[y[b] * 50 + tid];
    else if (tid < 122) W1s[tid - 50] = w1[tid - 50];
    else if (tid == 122) {
        double N = (double)BATCH * 936.0;
        double m = st0[0] / N;
        double var = st0[1] / N - m * m;
        double a = (double)g0[0] / sqrt(var + 1e-5);
        sa_s = (float)a;
        sc_s = (float)((double)b0[0] - m * a);
    }
    __syncthreads();
    float ls[8], lq[8];
#pragma unroll
    for (int o = 0; o < 8; o++) { ls[o] = 0.f; lq[o] = 0.f; }
    if (tid < 117) {
        float oc = bc[tid];
        for (int k = 0; k < 50; k++) oc = fmaf(embs[k], Wc[tid * 50 + k], oc);
        float h[9];
#pragma unroll
        for (int c = 0; c < 8; c++)
            h[c] = lrelu(fmaf(oi[(size_t)b * 936 + c * 117 + tid], sa_s, sc_s));
        h[8] = oc;
        float vn[8];
#pragma unroll
        for (int o = 0; o < 8; o++) {
            float a2 = 0.f;
#pragma unroll
            for (int c = 0; c < 9; c++) a2 = fmaf(W1s[o * 9 + c], h[c], a2);
            vn[o] = a2;
        }
        float* dp = v1 + ((size_t)b * 117 + tid) * 8;
        *(float4*)dp = make_float4(vn[0], vn[1], vn[2], vn[3]);
        *(float4*)(dp + 4) = make_float4(vn[4], vn[5], vn[6], vn[7]);
#pragma unroll
        for (int o = 0; o < 8; o++) vs[tid][o] = vn[o];
    }
    __syncthreads();
    if (tid < 117) {
        float csv = colsum1[tid];
        float4 bdv = band1[tid];
#pragma unroll
        for (int o = 0; o < 8; o++) {
            float v0 = vs[tid][o];
            ls[o] = fmaf(csv, v0, ls[o]);
            float t = bdv.x * v0;
            if (tid + 1 < 117) t = fmaf(bdv.y, vs[tid + 1][o], t);
            if (tid + 2 < 117) t = fmaf(bdv.z, vs[tid + 2][o], t);
            if (tid + 3 < 117) t = fmaf(bdv.w, vs[tid + 3][o], t);
            lq[o] = fmaf(v0, t, lq[o]);
        }
    }
#pragma unroll
    for (int o = 0; o < 8; o++)
        for (int off = 32; off > 0; off >>= 1) {
            ls[o] += __shfl_down(ls[o], off, 64);
            lq[o] += __shfl_down(lq[o], off, 64);
        }
    int wave = tid >> 6, lane = tid & 63;
    if (lane == 0)
#pragma unroll
        for (int o = 0; o < 8; o++) { red[wave][o] = ls[o]; red[wave][8 + o] = lq[o]; }
    __syncthreads();
    if (tid < 16)
        atomicAdd(&z1out[(b & 63) * 16 + tid], (double)(red[0][tid] + red[1][tid]));
}

// --------------------------------------------------- unified stage kernel ----
// One block per batch element; 8 chunks, 2 per WAVE (wave-private vs slice).
// R9 lesson: 16 block barriers/block + dependent ti0[j] L2 loads dominated.
// Now: 2 barriers total, inline tap weights, per-lane loops.
template <int LIN, int LOUT>
__global__ __launch_bounds__(256, 2) void k_stage(
    const float* __restrict__ vin, float* __restrict__ vout,
    const float* __restrict__ W, const float* __restrict__ coef,
    double* __restrict__ zout,
    const float* __restrict__ colsum, const float4* __restrict__ band)
{
    constexpr int JCW = (LOUT + 7) / 8;
    __shared__ float Ws[64], aa[8], cc[8];
    __shared__ float vins[LIN][9];
    __shared__ float vs[4][JCW + 3][9];
    __shared__ float red[4][16];
    int tid = threadIdx.x;
    int wave = tid >> 6, lane = tid & 63;
    if (tid < 64) Ws[tid] = W[tid];
    if (tid < 8) { aa[tid] = coef[tid]; cc[tid] = coef[8 + tid]; }
    int b = blockIdx.x;
    const float4* srcp = (const float4*)(vin + (size_t)b * LIN * 8);
    for (int f = tid; f < LIN * 2; f += 256) {
        float4 v = srcp[f];
        int q = f >> 1, hf = (f & 1) * 4;
        vins[q][hf + 0] = v.x; vins[q][hf + 1] = v.y;
        vins[q][hf + 2] = v.z; vins[q][hf + 3] = v.w;
    }
    float ls[8], lq[8];
#pragma unroll
    for (int o = 0; o < 8; o++) { ls[o] = 0.f; lq[o] = 0.f; }
    const float scale = (float)((double)LIN / (double)LOUT);
    __syncthreads();

    float (*vsw)[9] = vs[wave];
    for (int ch = wave; ch < 8; ch += 4) {
        int j0 = ch * JCW, j1 = min(j0 + JCW, LOUT);
        if (j0 >= LOUT) break;
        int je = min(j1 + 3, LOUT);
        // phase A (wave-private): upsample -> bn -> lrelu -> W -> vsw
        for (int jj = lane; jj < je - j0; jj += 64) {
            int j = j0 + jj;
            int i0;
            float wk[4];
            bicw(j, scale, i0, wk);
            float z[8] = {0.f, 0.f, 0.f, 0.f, 0.f, 0.f, 0.f, 0.f};
#pragma unroll
            for (int k = 0; k < 4; k++) {
                int q = min(max(i0 - 1 + k, 0), LIN - 1);
                const float* vp = vins[q];
#pragma unroll
                for (int c = 0; c < 8; c++) z[c] = fmaf(wk[k], vp[c], z[c]);
            }
            float h[8];
#pragma unroll
            for (int c = 0; c < 8; c++) h[c] = lrelu(fmaf(z[c], aa[c], cc[c]));
            float vn[8];
#pragma unroll
            for (int o = 0; o < 8; o++) {
                float a2 = 0.f;
#pragma unroll
                for (int c = 0; c < 8; c++) a2 = fmaf(Ws[o * 8 + c], h[c], a2);
                vn[o] = a2;
            }
            if (vout != nullptr && jj < j1 - j0) {
                float* dp = vout + ((size_t)b * LOUT + j) * 8;
                *(float4*)dp = make_float4(vn[0], vn[1], vn[2], vn[3]);
                *(float4*)(dp + 4) = make_float4(vn[4], vn[5], vn[6], vn[7]);
            }
#pragma unroll
            for (int o = 0; o < 8; o++) vsw[jj][o] = vn[o];
        }
        asm volatile("s_waitcnt lgkmcnt(0)" ::: "memory");  // wave-local A->B
        // phase B (wave-private): banded stats
        int nst = j1 - j0, ne = je - j0;
        for (int jj = lane; jj < nst; jj += 64) {
            int p = j0 + jj;
            float csv = colsum[p];
            float4 bdv = band[p];
#pragma unroll
            for (int o = 0; o < 8; o++) {
                float v0 = vsw[jj][o];
                ls[o] = fmaf(csv, v0, ls[o]);
                float t = bdv.x * v0;
                if (jj + 1 < ne) t = fmaf(bdv.y, vsw[jj + 1][o], t);
                if (jj + 2 < ne) t = fmaf(bdv.z, vsw[jj + 2][o], t);
                if (jj + 3 < ne) t = fmaf(bdv.w, vsw[jj + 3][o], t);
                lq[o] = fmaf(v0, t, lq[o]);
            }
        }
        asm volatile("s_waitcnt lgkmcnt(0)" ::: "memory");  // B done before reuse
    }

#pragma unroll
    for (int o = 0; o < 8; o++)
        for (int off = 32; off > 0; off >>= 1) {
            ls[o] += __shfl_down(ls[o], off, 64);
            lq[o] += __shfl_down(lq[o], off, 64);
        }
    if (lane == 0)
#pragma unroll
        for (int o = 0; o < 8; o++) { red[wave][o] = ls[o]; red[wave][8 + o] = lq[o]; }
    __syncthreads();
    if (tid < 16) {
        float v = red[0][tid] + red[1][tid] + red[2][tid] + red[3][tid];
        atomicAdd(&zout[(blockIdx.x & 63) * 16 + tid], (double)v);
    }
}

// ----------------- final: v4(LDS) -> h4 -> v5(wave-private LDS) -> out -----
__global__ __launch_bounds__(256, 2) void k_final(
    const float* __restrict__ v4, float* __restrict__ out,
    const float* __restrict__ W5, const float* __restrict__ w6,
    const float* __restrict__ coef4, const float* __restrict__ coef5)
{
    constexpr int JCW = (L5 + 7) / 8;    // 469
    __shared__ float W5s[64], w6s[8], a4[8], c4[8], a5[8], c5[8];
    __shared__ float v4s[L3][9];         // full v4 row, 33.7 KB
    __shared__ float v5s[4][242][9];     // per-wave p-range slices
    int tid = threadIdx.x;
    int wave = tid >> 6, lane = tid & 63;
    if (tid < 64) W5s[tid] = W5[tid];
    if (tid < 8) {
        w6s[tid] = w6[tid];
        a4[tid] = coef4[tid]; c4[tid] = coef4[8 + tid];
        a5[tid] = coef5[tid]; c5[tid] = coef5[8 + tid];
    }
    int b = blockIdx.x;
    const float4* srcp = (const float4*)(v4 + (size_t)b * L3 * 8);
    for (int f = tid; f < L3 * 2; f += 256) {
        float4 v = srcp[f];
        int q = f >> 1, hf = (f & 1) * 4;
        v4s[q][hf + 0] = v.x; v4s[q][hf + 1] = v.y;
        v4s[q][hf + 2] = v.z; v4s[q][hf + 3] = v.w;
    }
    const float scale4 = (float)((double)L3 / (double)L4);
    const float scale5 = (float)((double)L4 / (double)L5);
    __syncthreads();

    float (*v5w)[9] = v5s[wave];
    for (int ch = wave; ch < 8; ch += 4) {
        int j0 = ch * JCW, j1 = min(j0 + JCW, L5);
        if (j0 >= L5) break;
        int i0a, i0b;
        float wt[4];
        bicw(j0, scale5, i0a, wt);
        bicw(j1 - 1, scale5, i0b, wt);
        int plo = max(0, i0a - 1);
        int phi = min(L4 - 1, i0b + 2);
        int NP = phi - plo + 1;
        // phase A (wave-private): v5 for p-range from LDS v4
        for (int pp = lane; pp < NP; pp += 64) {
            int p = plo + pp;
            int i0;
            float wk[4];
            bicw(p, scale4, i0, wk);
            float z[8] = {0.f, 0.f, 0.f, 0.f, 0.f, 0.f, 0.f, 0.f};
#pragma unroll
            for (int k = 0; k < 4; k++) {
                int q = min(max(i0 - 1 + k, 0), L3 - 1);
                const float* vp = v4s[q];
#pragma unroll
                for (int c = 0; c < 8; c++) z[c] = fmaf(wk[k], vp[c], z[c]);
            }
            float h[8];
#pragma unroll
            for (int c = 0; c < 8; c++) h[c] = lrelu(fmaf(z[c], a4[c], c4[c]));
#pragma unroll
            for (int o = 0; o < 8; o++) {
                float a2 = 0.f;
#pragma unroll
                for (int c = 0; c < 8; c++) a2 = fmaf(W5s[o * 8 + c], h[c], a2);
                v5w[pp][o] = a2;
            }
        }
        asm volatile("s_waitcnt lgkmcnt(0)" ::: "memory");  // wave-local A->B
        // phase B (wave-private): upsample v5 -> bn5 -> lrelu -> dot w6 -> out
        for (int jj = lane; jj < j1 - j0; jj += 64) {
            int j = j0 + jj;
            int i0;
            float wk[4];
            bicw(j, scale5, i0, wk);
            float z[8] = {0.f, 0.f, 0.f, 0.f, 0.f, 0.f, 0.f, 0.f};
#pragma unroll
            for (int k = 0; k < 4; k++) {
                int pp = min(max(i0 - 1 + k, 0), L4 - 1) - plo;
                const float* vp = v5w[pp];
#pragma unroll
                for (int o = 0; o < 8; o++) z[o] = fmaf(wk[k], vp[o], z[o]);
            }
            float r = 0.f;
#pragma unroll
            for (int o = 0; o < 8; o++)
                r = fmaf(w6s[o], lrelu(fmaf(z[o], a5[o], c5[o])), r);
            out[(size_t)b * L5 + j] = r;
        }
        asm volatile("s_waitcnt lgkmcnt(0)" ::: "memory");  // B done before reuse
    }
}

// ---------------------------------------------------------------- launch ----
extern "C" void kernel_launch(void* const* d_in, const int* in_sizes, int n_in,
                              void* d_out, int out_size, void* d_ws, size_t ws_size,
                              hipStream_t stream)
{
    const float* x   = (const float*)d_in[0];
    const int*   y   = (const int*)d_in[1];
    const float* emb = (const float*)d_in[2];
    const float* Wc  = (const float*)d_in[3];
    const float* bc  = (const float*)d_in[4];
    const float* Wi  = (const float*)d_in[5];
    const float* bi  = (const float*)d_in[6];
    const float* g0  = (const float*)d_in[7];
    const float* b0  = (const float*)d_in[8];
    const float* w1  = (const float*)d_in[9];
    const float* w2  = (const float*)d_in[10];
    const float* w3  = (const float*)d_in[11];
    const float* w4  = (const float*)d_in[12];
    const float* w5  = (const float*)d_in[13];
    const float* w6  = (const float*)d_in[14];
    const float* g1  = (const float*)d_in[15];
    const float* b1  = (const float*)d_in[16];
    const float* g2  = (const float*)d_in[17];
    const float* b2  = (const float*)d_in[18];
    const float* g3  = (const float*)d_in[19];
    const float* b3  = (const float*)d_in[20];
    const float* g4  = (const float*)d_in[21];
    const float* b4  = (const float*)d_in[22];
    const float* g5  = (const float*)d_in[23];
    const float* b5  = (const float*)d_in[24];
    float* out = (float*)d_out;

    char* ws = (char*)d_ws;
    size_t off = 0;
    auto alloc = [&](size_t bytes) {
        size_t r = off;
        off += (bytes + 255) & ~(size_t)255;
        return r;
    };
    double* stats  = (double*)(ws + alloc(NSTATS * sizeof(double)));
    float*  coefs  = (float*)(ws + alloc(5 * 16 * sizeof(float)));
    float*  colsum = (float*)(ws + alloc((size_t)NBT * sizeof(float)));
    float4* band   = (float4*)(ws + alloc((size_t)NBT * sizeof(float4)));
    float*  oi     = (float*)(ws + alloc((size_t)BATCH * 936 * 4));
    float*  bufA   = (float*)(ws + alloc((size_t)BATCH * L2 * 8 * 4));   // v1 / v3
    float*  bufB   = (float*)(ws + alloc((size_t)BATCH * L3 * 8 * 4));   // v2 / v4

    double* st0  = stats;
    double* zst1 = stats + 16;
    double* zst2 = stats + 16 + 1024;
    double* zst3 = stats + 16 + 2048;
    double* zst4 = stats + 16 + 3072;
    double* zst5 = stats + 16 + 4096;
    float* coef1 = coefs +  0;
    float* coef2 = coefs + 16;
    float* coef3 = coefs + 32;
    float* coef4 = coefs + 48;
    float* coef5 = coefs + 64;

    const int t1 = 0, t2 = L0, t3 = L0 + L1, t4 = L0 + L1 + L2, t5 = L0 + L1 + L2 + L3;

    float* v1 = bufA;
    float* v2 = bufB;
    float* v3 = bufA;
    float* v4 = bufB;

    k_setup<<<1, 256, 0, stream>>>(stats);
    k_setup2<<<5, 256, 0, stream>>>(colsum, band);
    k0a<<<dim3(8, 64), 256, 0, stream>>>(x, Wi, bi, oi, st0);
    k0b<<<BATCH, 128, 0, stream>>>(oi, emb, y, Wc, bc, g0, b0, w1, st0, zst1,
                                   colsum + t1, band + t1, v1);
    k_coef<<<1, 64, 0, stream>>>(zst1, g1, b1, (double)BATCH * L1, coef1);
    k_stage<L0, L1><<<BATCH, 256, 0, stream>>>(v1, v2, w2, coef1, zst2,
                                               colsum + t2, band + t2);
    k_coef<<<1, 64, 0, stream>>>(zst2, g2, b2, (double)BATCH * L2, coef2);
    k_stage<L1, L2><<<BATCH, 256, 0, stream>>>(v2, v3, w3, coef2, zst3,
                                               colsum + t3, band + t3);
    k_coef<<<1, 64, 0, stream>>>(zst3, g3, b3, (double)BATCH * L3, coef3);
    k_stage<L2, L3><<<BATCH, 256, 0, stream>>>(v3, v4, w4, coef3, zst4,
                                               colsum + t4, band + t4);
    k_coef<<<1, 64, 0, stream>>>(zst4, g4, b4, (double)BATCH * L4, coef4);
    k_stage<L3, L4><<<BATCH, 256, 0, stream>>>(v4, nullptr, w5, coef4, zst5,
                                               colsum + t5, band + t5);
    k_coef<<<1, 64, 0, stream>>>(zst5, g5, b5, (double)BATCH * L5, coef5);
    k_final<<<BATCH, 256, 0, stream>>>(v4, out, w5, w6, coef4, coef5);
}